// Round 1
// baseline (1672.573 us; speedup 1.0000x reference)
//
#include <hip/hip_runtime.h>
#include <hip/hip_bf16.h>
#include <math.h>

#define NODES 50000
#define NEDGE 800000

typedef __bf16 bf16_t;
typedef __bf16 bf16x8 __attribute__((ext_vector_type(8)));
typedef float floatx4 __attribute__((ext_vector_type(4)));

__device__ __forceinline__ float bfbits2f(unsigned int hi16) {
    union { unsigned int u; float f; } c; c.u = hi16; return c.f;
}

// 0=none, 1=relu, 2=gelu(erf, exact), 3=softplus
template<int ACT>
__device__ __forceinline__ float act_fn(float v) {
    if (ACT == 1) return fmaxf(v, 0.f);
    if (ACT == 2) return 0.5f * v * (1.f + erff(v * 0.70710678118654752f));
    if (ACT == 3) return (v > 20.f) ? v : log1pf(expf(v));
    return v;
}

// ---------------------------------------------------------------------------
// Weight prep: 9 matrices W[k][n] fp32 -> Wt[n][k] bf16 (transposed)
// ---------------------------------------------------------------------------
__global__ __launch_bounds__(256) void prep_weights(
    const float* __restrict__ w0, const float* __restrict__ w1,
    const float* __restrict__ w2, const float* __restrict__ w3,
    const float* __restrict__ w4, const float* __restrict__ w5,
    const float* __restrict__ w6, const float* __restrict__ w7,
    const float* __restrict__ w8, bf16_t* __restrict__ wt)
{
    const float* Ws[9] = {w0, w1, w2, w3, w4, w5, w6, w7, w8};
    const float* W = Ws[blockIdx.x];
    bf16_t* o = wt + blockIdx.x * 16384;
    for (int idx = threadIdx.x; idx < 16384; idx += 256) {
        int k = idx >> 7, n = idx & 127;
        o[n * 128 + k] = (bf16_t)W[idx];   // coalesced read, scattered write (tiny)
    }
}

// ---------------------------------------------------------------------------
// GEMM: C[M,128] = act(A[M,128] @ W[128,128] + bias) (+res), MFMA 16x16x32 bf16
// Tile 128x128 per block, 4 waves each 64x64 (4x4 of 16x16).
// LDS XOR-swizzle (granule g of row r stored at g^(r&15)) -> 2-way max conflict.
// ---------------------------------------------------------------------------
template<int ACT, bool A_F32, bool OUT_BF16, bool ADD_RES>
__global__ __launch_bounds__(256, 2) void gemm128(
    const void* __restrict__ Av,
    const bf16_t* __restrict__ Wt,    // [n][k] transposed bf16
    const float* __restrict__ bias,
    void* __restrict__ Out,
    const float* __restrict__ res,
    int M)
{
    __shared__ __align__(16) bf16_t As[128 * 128];
    __shared__ __align__(16) bf16_t Bs[128 * 128];
    const int t = threadIdx.x;
    const int r0 = blockIdx.x * 128;

    // stage W (always full 128x128)
    for (int i = 0; i < 8; ++i) {
        int c = t + i * 256;
        int row = c >> 4, g = c & 15;
        uint4 v = *(const uint4*)(Wt + row * 128 + g * 8);
        *(uint4*)&Bs[row * 128 + ((g ^ (row & 15)) * 8)] = v;
    }
    if (A_F32) {
        const float* A = (const float*)Av;
        for (int i = 0; i < 16; ++i) {
            int c = t + i * 256;
            int row = c >> 5, c4 = c & 31;
            int gr = r0 + row;
            float4 v = make_float4(0.f, 0.f, 0.f, 0.f);
            if (gr < M) v = *(const float4*)(A + (size_t)gr * 128 + c4 * 4);
            int g = c4 >> 1, half = c4 & 1;
            bf16_t* d = &As[row * 128 + (g ^ (row & 15)) * 8 + half * 4];
            d[0] = (bf16_t)v.x; d[1] = (bf16_t)v.y;
            d[2] = (bf16_t)v.z; d[3] = (bf16_t)v.w;
        }
    } else {
        const bf16_t* A = (const bf16_t*)Av;
        for (int i = 0; i < 8; ++i) {
            int c = t + i * 256;
            int row = c >> 4, g = c & 15;
            int gr = r0 + row;
            uint4 v = make_uint4(0, 0, 0, 0);
            if (gr < M) v = *(const uint4*)(A + (size_t)gr * 128 + g * 8);
            *(uint4*)&As[row * 128 + ((g ^ (row & 15)) * 8)] = v;
        }
    }
    __syncthreads();

    const int lane = t & 63;
    const int wave = t >> 6;
    const int wm = (wave & 1) * 64;
    const int wn = (wave >> 1) * 64;
    const int l15 = lane & 15;
    const int quad = lane >> 4;

    floatx4 acc[4][4];
    for (int mi = 0; mi < 4; ++mi)
        for (int ni = 0; ni < 4; ++ni)
            for (int r = 0; r < 4; ++r) acc[mi][ni][r] = 0.f;

    for (int k0 = 0; k0 < 128; k0 += 32) {
        const int kg = (k0 >> 3) + quad;   // k-granule for this quad: A[m][k=quad*8+j]
        bf16x8 a[4], b[4];
        for (int mi = 0; mi < 4; ++mi) {
            int row = wm + mi * 16 + l15;
            a[mi] = *(const bf16x8*)&As[row * 128 + ((kg ^ (row & 15)) * 8)];
        }
        for (int ni = 0; ni < 4; ++ni) {
            int row = wn + ni * 16 + l15;
            b[ni] = *(const bf16x8*)&Bs[row * 128 + ((kg ^ (row & 15)) * 8)];
        }
        for (int mi = 0; mi < 4; ++mi)
            for (int ni = 0; ni < 4; ++ni)
                acc[mi][ni] = __builtin_amdgcn_mfma_f32_16x16x32_bf16(
                    a[mi], b[ni], acc[mi][ni], 0, 0, 0);
    }

    // epilogue: C[m=quad*4+r][n=lane&15] per 16x16 tile (m89/m91-verified layout)
    for (int mi = 0; mi < 4; ++mi) {
        for (int r = 0; r < 4; ++r) {
            int row = wm + mi * 16 + quad * 4 + r;
            int gr = r0 + row;
            if (gr < M) {
                for (int ni = 0; ni < 4; ++ni) {
                    int col = wn + ni * 16 + l15;
                    float v = acc[mi][ni][r] + bias[col];
                    v = act_fn<ACT>(v);
                    if (ADD_RES) v += res[(size_t)gr * 128 + col];
                    if (OUT_BF16) ((bf16_t*)Out)[(size_t)gr * 128 + col] = (bf16_t)v;
                    else          ((float*)Out)[(size_t)gr * 128 + col] = v;
                }
            }
        }
    }
}

// ---------------------------------------------------------------------------
// LayerNorm: one wave per row of h (bf16) -> x_res fp32
// ---------------------------------------------------------------------------
__global__ __launch_bounds__(256) void ln_kernel(
    const bf16_t* __restrict__ h, const float* __restrict__ g,
    const float* __restrict__ b, float* __restrict__ out, int M)
{
    int wave = threadIdx.x >> 6, lane = threadIdx.x & 63;
    int row = blockIdx.x * 4 + wave;
    if (row >= M) return;
    size_t i0 = (size_t)row * 128 + lane * 2;
    float f0 = (float)h[i0], f1 = (float)h[i0 + 1];
    float s = f0 + f1, sq = f0 * f0 + f1 * f1;
    for (int o = 1; o < 64; o <<= 1) {
        s  += __shfl_xor(s, o, 64);
        sq += __shfl_xor(sq, o, 64);
    }
    float m  = s * (1.f / 128.f);
    float var = fmaxf(sq * (1.f / 128.f) - m * m, 0.f);
    float rs = rsqrtf(var + 1e-5f);
    out[i0]     = (f0 - m) * rs * g[lane * 2]     + b[lane * 2];
    out[i0 + 1] = (f1 - m) * rs * g[lane * 2 + 1] + b[lane * 2 + 1];
}

// ---------------------------------------------------------------------------
// Scatter: agg[dst] += h[src] over E edges; 32 threads/edge, 4 dims each
// ---------------------------------------------------------------------------
__global__ __launch_bounds__(256) void scatter_kernel(
    const int* __restrict__ ei, const bf16_t* __restrict__ h,
    float* __restrict__ agg, int E)
{
    int idx = blockIdx.x * 256 + threadIdx.x;
    int e = idx >> 5, q = idx & 31;
    if (e >= E) return;
    int src = ei[e], dst = ei[E + e];
    uint2 raw = *(const uint2*)(h + (size_t)src * 128 + q * 4);
    float* ap = agg + (size_t)dst * 128 + q * 4;
    unsafeAtomicAdd(ap + 0, bfbits2f(raw.x << 16));
    unsafeAtomicAdd(ap + 1, bfbits2f(raw.x & 0xffff0000u));
    unsafeAtomicAdd(ap + 2, bfbits2f(raw.y << 16));
    unsafeAtomicAdd(ap + 3, bfbits2f(raw.y & 0xffff0000u));
}

// ---------------------------------------------------------------------------
// y = (beta*agg + gamma) / (alpha + beta*degree), 4 elems/thread -> bf16
// ---------------------------------------------------------------------------
__global__ __launch_bounds__(256) void y_kernel(
    const bf16_t* __restrict__ al, const bf16_t* __restrict__ be,
    const bf16_t* __restrict__ ga, const float* __restrict__ agg,
    const float* __restrict__ deg, bf16_t* __restrict__ y, int M)
{
    int i4 = blockIdx.x * 256 + threadIdx.x;
    size_t i = (size_t)i4 * 4;
    if (i >= (size_t)M * 128) return;
    float d = deg[i >> 7];
    float4 ag = *(const float4*)(agg + i);
    float agv[4] = {ag.x, ag.y, ag.z, ag.w};
    for (int j = 0; j < 4; ++j) {
        float a = (float)al[i + j], b = (float)be[i + j], g = (float)ga[i + j];
        y[i + j] = (bf16_t)((b * agv[j] + g) / (a + b * d));
    }
}

// ---------------------------------------------------------------------------
extern "C" void kernel_launch(void* const* d_in, const int* in_sizes, int n_in,
                              void* d_out, int out_size, void* d_ws, size_t ws_size,
                              hipStream_t stream)
{
    const float* x    = (const float*)d_in[0];
    const int*   ei   = (const int*)d_in[1];
    const float* deg  = (const float*)d_in[2];
    const float* W_lin = (const float*)d_in[3];  const float* b_lin = (const float*)d_in[4];
    const float* Wa1 = (const float*)d_in[5];    const float* ba1 = (const float*)d_in[6];
    const float* Wa2 = (const float*)d_in[7];    const float* ba2 = (const float*)d_in[8];
    const float* Wb1 = (const float*)d_in[9];    const float* bb1 = (const float*)d_in[10];
    const float* Wb2 = (const float*)d_in[11];   const float* bb2 = (const float*)d_in[12];
    const float* Wg1 = (const float*)d_in[13];   const float* bg1 = (const float*)d_in[14];
    const float* Wg2 = (const float*)d_in[15];   const float* bg2 = (const float*)d_in[16];
    const float* Wf1 = (const float*)d_in[17];   const float* bf1 = (const float*)d_in[18];
    const float* Wf2 = (const float*)d_in[19];   const float* bf2 = (const float*)d_in[20];
    const float* ln_g = (const float*)d_in[21];  const float* ln_b = (const float*)d_in[22];

    const int M = NODES;
    const size_t NB2 = (size_t)M * 128 * 2;   // bf16 [N,128]
    const size_t NB4 = (size_t)M * 128 * 4;   // f32  [N,128]

    char* ws = (char*)d_ws;
    size_t off = 0;
    bf16_t* wt  = (bf16_t*)(ws + off); off += (size_t)9 * 16384 * 2;
    bf16_t* h   = (bf16_t*)(ws + off); off += NB2;
    float*  agg = (float*)(ws + off);  off += NB4;
    bf16_t* ta  = (bf16_t*)(ws + off); off += NB2;
    bf16_t* tb  = (bf16_t*)(ws + off); off += NB2;
    bf16_t* tg  = (bf16_t*)(ws + off); off += NB2;
    bf16_t* al  = (bf16_t*)(ws + off); off += NB2;
    bf16_t* be  = (bf16_t*)(ws + off); off += NB2;
    bf16_t* ga  = (bf16_t*)(ws + off); off += NB2;
    bf16_t* yv  = (bf16_t*)(ws + off); off += NB2;
    bf16_t* tf  = (bf16_t*)(ws + off); off += NB2;
    float* xres = (float*)d_out;   // d_out doubles as x_res scratch
    float* outp = (float*)d_out;

    dim3 blk(256);
    int gB = (M + 127) / 128;   // 391

    prep_weights<<<9, blk, 0, stream>>>(W_lin, Wa1, Wa2, Wb1, Wb2, Wg1, Wg2, Wf1, Wf2, wt);
    hipMemsetAsync(agg, 0, NB4, stream);

    // h = x @ W_lin + b_lin  (fp32 in, bf16 out)
    gemm128<0, true,  true,  false><<<gB, blk, 0, stream>>>(x, wt + 0 * 16384, b_lin, h, nullptr, M);
    // x_res = LN(h)
    ln_kernel<<<(M + 3) / 4, blk, 0, stream>>>(h, ln_g, ln_b, xres, M);
    // agg = segment_sum(h[src], dst)
    scatter_kernel<<<(NEDGE * 32) / 256, blk, 0, stream>>>(ei, h, agg, NEDGE);
    // first-layer branches
    gemm128<1, false, true, false><<<gB, blk, 0, stream>>>(h, wt + 1 * 16384, ba1, ta, nullptr, M);
    gemm128<1, false, true, false><<<gB, blk, 0, stream>>>(h, wt + 3 * 16384, bb1, tb, nullptr, M);
    gemm128<2, false, true, false><<<gB, blk, 0, stream>>>(h, wt + 5 * 16384, bg1, tg, nullptr, M);
    // second-layer branches
    gemm128<3, false, true, false><<<gB, blk, 0, stream>>>(ta, wt + 2 * 16384, ba2, al, nullptr, M);
    gemm128<3, false, true, false><<<gB, blk, 0, stream>>>(tb, wt + 4 * 16384, bb2, be, nullptr, M);
    gemm128<0, false, true, false><<<gB, blk, 0, stream>>>(tg, wt + 6 * 16384, bg2, ga, nullptr, M);
    // y
    y_kernel<<<(M * 128 / 4 + 255) / 256, blk, 0, stream>>>(al, be, ga, agg, deg, yv, M);
    // final MLP + residual
    gemm128<2, false, true,  false><<<gB, blk, 0, stream>>>(yv, wt + 7 * 16384, bf1, tf, nullptr, M);
    gemm128<0, false, false, true ><<<gB, blk, 0, stream>>>(tf, wt + 8 * 16384, bf2, outp, xres, M);
}

// Round 2
// 472.151 us; speedup vs baseline: 3.5425x; 3.5425x over previous
//
#include <hip/hip_runtime.h>
#include <hip/hip_bf16.h>
#include <math.h>

#define NODES 50000
#define NEDGE 800000
#define NBLK_SCAN ((NODES + 255) / 256)   // 196

typedef __bf16 bf16_t;
typedef __bf16 bf16x8 __attribute__((ext_vector_type(8)));
typedef float floatx4 __attribute__((ext_vector_type(4)));

__device__ __forceinline__ float bfbits2f(unsigned int hi16) {
    union { unsigned int u; float f; } c; c.u = hi16; return c.f;
}

// 0=none, 1=relu, 2=gelu(erf, exact), 3=softplus
template<int ACT>
__device__ __forceinline__ float act_fn(float v) {
    if (ACT == 1) return fmaxf(v, 0.f);
    if (ACT == 2) return 0.5f * v * (1.f + erff(v * 0.70710678118654752f));
    if (ACT == 3) return (v > 20.f) ? v : log1pf(expf(v));
    return v;
}

// ---------------------------------------------------------------------------
// Weight prep: 9 matrices W[k][n] fp32 -> Wt[n][k] bf16 (transposed)
// ---------------------------------------------------------------------------
__global__ __launch_bounds__(256) void prep_weights(
    const float* __restrict__ w0, const float* __restrict__ w1,
    const float* __restrict__ w2, const float* __restrict__ w3,
    const float* __restrict__ w4, const float* __restrict__ w5,
    const float* __restrict__ w6, const float* __restrict__ w7,
    const float* __restrict__ w8, bf16_t* __restrict__ wt)
{
    const float* Ws[9] = {w0, w1, w2, w3, w4, w5, w6, w7, w8};
    const float* W = Ws[blockIdx.x];
    bf16_t* o = wt + blockIdx.x * 16384;
    for (int idx = threadIdx.x; idx < 16384; idx += 256) {
        int k = idx >> 7, n = idx & 127;
        o[n * 128 + k] = (bf16_t)W[idx];
    }
}

// ---------------------------------------------------------------------------
// GEMM: C[M,128] = act(A[M,128] @ W[128,128] + bias) (+res), MFMA 16x16x32 bf16
// ---------------------------------------------------------------------------
template<int ACT, bool A_F32, bool OUT_BF16, bool ADD_RES>
__global__ __launch_bounds__(256, 2) void gemm128(
    const void* __restrict__ Av,
    const bf16_t* __restrict__ Wt,    // [n][k] transposed bf16
    const float* __restrict__ bias,
    void* __restrict__ Out,
    const float* __restrict__ res,
    int M)
{
    __shared__ __align__(16) bf16_t As[128 * 128];
    __shared__ __align__(16) bf16_t Bs[128 * 128];
    const int t = threadIdx.x;
    const int r0 = blockIdx.x * 128;

    for (int i = 0; i < 8; ++i) {
        int c = t + i * 256;
        int row = c >> 4, g = c & 15;
        uint4 v = *(const uint4*)(Wt + row * 128 + g * 8);
        *(uint4*)&Bs[row * 128 + ((g ^ (row & 15)) * 8)] = v;
    }
    if (A_F32) {
        const float* A = (const float*)Av;
        for (int i = 0; i < 16; ++i) {
            int c = t + i * 256;
            int row = c >> 5, c4 = c & 31;
            int gr = r0 + row;
            float4 v = make_float4(0.f, 0.f, 0.f, 0.f);
            if (gr < M) v = *(const float4*)(A + (size_t)gr * 128 + c4 * 4);
            int g = c4 >> 1, half = c4 & 1;
            bf16_t* d = &As[row * 128 + (g ^ (row & 15)) * 8 + half * 4];
            d[0] = (bf16_t)v.x; d[1] = (bf16_t)v.y;
            d[2] = (bf16_t)v.z; d[3] = (bf16_t)v.w;
        }
    } else {
        const bf16_t* A = (const bf16_t*)Av;
        for (int i = 0; i < 8; ++i) {
            int c = t + i * 256;
            int row = c >> 4, g = c & 15;
            int gr = r0 + row;
            uint4 v = make_uint4(0, 0, 0, 0);
            if (gr < M) v = *(const uint4*)(A + (size_t)gr * 128 + g * 8);
            *(uint4*)&As[row * 128 + ((g ^ (row & 15)) * 8)] = v;
        }
    }
    __syncthreads();

    const int lane = t & 63;
    const int wave = t >> 6;
    const int wm = (wave & 1) * 64;
    const int wn = (wave >> 1) * 64;
    const int l15 = lane & 15;
    const int quad = lane >> 4;

    floatx4 acc[4][4];
    for (int mi = 0; mi < 4; ++mi)
        for (int ni = 0; ni < 4; ++ni)
            for (int r = 0; r < 4; ++r) acc[mi][ni][r] = 0.f;

    for (int k0 = 0; k0 < 128; k0 += 32) {
        const int kg = (k0 >> 3) + quad;
        bf16x8 a[4], b[4];
        for (int mi = 0; mi < 4; ++mi) {
            int row = wm + mi * 16 + l15;
            a[mi] = *(const bf16x8*)&As[row * 128 + ((kg ^ (row & 15)) * 8)];
        }
        for (int ni = 0; ni < 4; ++ni) {
            int row = wn + ni * 16 + l15;
            b[ni] = *(const bf16x8*)&Bs[row * 128 + ((kg ^ (row & 15)) * 8)];
        }
        for (int mi = 0; mi < 4; ++mi)
            for (int ni = 0; ni < 4; ++ni)
                acc[mi][ni] = __builtin_amdgcn_mfma_f32_16x16x32_bf16(
                    a[mi], b[ni], acc[mi][ni], 0, 0, 0);
    }

    for (int mi = 0; mi < 4; ++mi) {
        for (int r = 0; r < 4; ++r) {
            int row = wm + mi * 16 + quad * 4 + r;
            int gr = r0 + row;
            if (gr < M) {
                for (int ni = 0; ni < 4; ++ni) {
                    int col = wn + ni * 16 + l15;
                    float v = acc[mi][ni][r] + bias[col];
                    v = act_fn<ACT>(v);
                    if (ADD_RES) v += res[(size_t)gr * 128 + col];
                    if (OUT_BF16) ((bf16_t*)Out)[(size_t)gr * 128 + col] = (bf16_t)v;
                    else          ((float*)Out)[(size_t)gr * 128 + col] = v;
                }
            }
        }
    }
}

// ---------------------------------------------------------------------------
// LayerNorm: one wave per row of h (bf16) -> x_res fp32
// ---------------------------------------------------------------------------
__global__ __launch_bounds__(256) void ln_kernel(
    const bf16_t* __restrict__ h, const float* __restrict__ g,
    const float* __restrict__ b, float* __restrict__ out, int M)
{
    int wave = threadIdx.x >> 6, lane = threadIdx.x & 63;
    int row = blockIdx.x * 4 + wave;
    if (row >= M) return;
    size_t i0 = (size_t)row * 128 + lane * 2;
    float f0 = (float)h[i0], f1 = (float)h[i0 + 1];
    float s = f0 + f1, sq = f0 * f0 + f1 * f1;
    for (int o = 1; o < 64; o <<= 1) {
        s  += __shfl_xor(s, o, 64);
        sq += __shfl_xor(sq, o, 64);
    }
    float m  = s * (1.f / 128.f);
    float var = fmaxf(sq * (1.f / 128.f) - m * m, 0.f);
    float rs = rsqrtf(var + 1e-5f);
    out[i0]     = (f0 - m) * rs * g[lane * 2]     + b[lane * 2];
    out[i0 + 1] = (f1 - m) * rs * g[lane * 2 + 1] + b[lane * 2 + 1];
}

// ---------------------------------------------------------------------------
// Counting sort of edges by dst: histogram -> scan -> reorder
// ---------------------------------------------------------------------------
__global__ __launch_bounds__(256) void hist_kernel(const int* __restrict__ ei,
                                                   int* __restrict__ cnt)
{
    int e = blockIdx.x * 256 + threadIdx.x;
    if (e < NEDGE) atomicAdd(&cnt[ei[NEDGE + e]], 1);
}

__global__ __launch_bounds__(256) void scan1_kernel(const int* __restrict__ cnt,
        int* __restrict__ offs, int* __restrict__ bsum)
{
    __shared__ int sd[256];
    int tid = threadIdx.x;
    int i = blockIdx.x * 256 + tid;
    int v = (i < NODES) ? cnt[i] : 0;
    sd[tid] = v;
    __syncthreads();
    for (int o = 1; o < 256; o <<= 1) {
        int other = (tid >= o) ? sd[tid - o] : 0;
        __syncthreads();
        sd[tid] += other;
        __syncthreads();
    }
    if (i < NODES) offs[i] = sd[tid] - v;   // exclusive within block
    if (tid == 255) bsum[blockIdx.x] = sd[255];
}

__global__ __launch_bounds__(256) void scan2_kernel(const int* __restrict__ bsum,
                                                    int* __restrict__ bofs)
{
    __shared__ int sd[256];
    int tid = threadIdx.x;
    int v = (tid < NBLK_SCAN) ? bsum[tid] : 0;
    sd[tid] = v;
    __syncthreads();
    for (int o = 1; o < 256; o <<= 1) {
        int other = (tid >= o) ? sd[tid - o] : 0;
        __syncthreads();
        sd[tid] += other;
        __syncthreads();
    }
    if (tid < NBLK_SCAN) bofs[tid] = sd[tid] - v;
}

__global__ __launch_bounds__(256) void scan3_kernel(const int* __restrict__ offs,
        const int* __restrict__ bofs, int* __restrict__ off_start,
        int* __restrict__ cur)
{
    int i = blockIdx.x * 256 + threadIdx.x;
    if (i < NODES) {
        int v = offs[i] + bofs[blockIdx.x];
        off_start[i] = v;
        cur[i] = v;
    }
}

__global__ __launch_bounds__(256) void reorder_kernel(const int* __restrict__ ei,
        int* __restrict__ cur, int* __restrict__ srcs)
{
    int e = blockIdx.x * 256 + threadIdx.x;
    if (e >= NEDGE) return;
    int dst = ei[NEDGE + e];
    int pos = atomicAdd(&cur[dst], 1);
    srcs[pos] = ei[e];
}

// ---------------------------------------------------------------------------
// Gather + y epilogue: one wave per node.
//   agg[node] = sum_{src in CSR list} h[src]  (fp32 regs, coalesced 256B loads)
//   y = (beta*agg + gamma) / (alpha + beta*degree)  -> bf16
// ---------------------------------------------------------------------------
__global__ __launch_bounds__(256) void gather_y_kernel(
    const int* __restrict__ off_start, const int* __restrict__ cnt,
    const int* __restrict__ srcs, const bf16_t* __restrict__ h,
    const bf16_t* __restrict__ al, const bf16_t* __restrict__ be,
    const bf16_t* __restrict__ ga, const float* __restrict__ deg,
    bf16_t* __restrict__ y, int M)
{
    int wave = threadIdx.x >> 6, lane = threadIdx.x & 63;
    int node = blockIdx.x * 4 + wave;
    if (node >= M) return;
    int s0 = off_start[node];
    int n  = cnt[node];
    float a0 = 0.f, a1 = 0.f;
    for (int j = 0; j < n; j += 64) {
        int m = min(64, n - j);
        int myv = (j + lane < n) ? srcs[s0 + j + lane] : 0;
        for (int t = 0; t < m; ++t) {
            int src = __shfl(myv, t, 64);
            unsigned raw = *(const unsigned*)(h + (size_t)src * 128 + lane * 2);
            a0 += bfbits2f(raw << 16);
            a1 += bfbits2f(raw & 0xffff0000u);
        }
    }
    size_t i0 = (size_t)node * 128 + (size_t)lane * 2;
    unsigned ra = *(const unsigned*)(al + i0);
    unsigned rb = *(const unsigned*)(be + i0);
    unsigned rg = *(const unsigned*)(ga + i0);
    float d = deg[node];
    float al0 = bfbits2f(ra << 16), al1 = bfbits2f(ra & 0xffff0000u);
    float b0  = bfbits2f(rb << 16), b1  = bfbits2f(rb & 0xffff0000u);
    float g0  = bfbits2f(rg << 16), g1  = bfbits2f(rg & 0xffff0000u);
    float y0 = (b0 * a0 + g0) / (al0 + b0 * d);
    float y1 = (b1 * a1 + g1) / (al1 + b1 * d);
    unsigned out;
    __bf16 o0 = (bf16_t)y0, o1 = (bf16_t)y1;
    unsigned u0 = *(unsigned short*)&o0, u1 = *(unsigned short*)&o1;
    out = u0 | (u1 << 16);
    *(unsigned*)(y + i0) = out;
}

// ---------------------------------------------------------------------------
extern "C" void kernel_launch(void* const* d_in, const int* in_sizes, int n_in,
                              void* d_out, int out_size, void* d_ws, size_t ws_size,
                              hipStream_t stream)
{
    const float* x    = (const float*)d_in[0];
    const int*   ei   = (const int*)d_in[1];
    const float* deg  = (const float*)d_in[2];
    const float* W_lin = (const float*)d_in[3];  const float* b_lin = (const float*)d_in[4];
    const float* Wa1 = (const float*)d_in[5];    const float* ba1 = (const float*)d_in[6];
    const float* Wa2 = (const float*)d_in[7];    const float* ba2 = (const float*)d_in[8];
    const float* Wb1 = (const float*)d_in[9];    const float* bb1 = (const float*)d_in[10];
    const float* Wb2 = (const float*)d_in[11];   const float* bb2 = (const float*)d_in[12];
    const float* Wg1 = (const float*)d_in[13];   const float* bg1 = (const float*)d_in[14];
    const float* Wg2 = (const float*)d_in[15];   const float* bg2 = (const float*)d_in[16];
    const float* Wf1 = (const float*)d_in[17];   const float* bf1 = (const float*)d_in[18];
    const float* Wf2 = (const float*)d_in[19];   const float* bf2 = (const float*)d_in[20];
    const float* ln_g = (const float*)d_in[21];  const float* ln_b = (const float*)d_in[22];

    const int M = NODES;
    const size_t NB2 = (size_t)M * 128 * 2;   // bf16 [N,128]

    char* ws = (char*)d_ws;
    size_t off = 0;
    bf16_t* wt  = (bf16_t*)(ws + off); off += (size_t)9 * 16384 * 2;
    bf16_t* h   = (bf16_t*)(ws + off); off += NB2;
    bf16_t* ta  = (bf16_t*)(ws + off); off += NB2;
    bf16_t* tb  = (bf16_t*)(ws + off); off += NB2;
    bf16_t* tg  = (bf16_t*)(ws + off); off += NB2;
    bf16_t* al  = (bf16_t*)(ws + off); off += NB2;
    bf16_t* be  = (bf16_t*)(ws + off); off += NB2;
    bf16_t* ga  = (bf16_t*)(ws + off); off += NB2;
    bf16_t* yv  = (bf16_t*)(ws + off); off += NB2;
    bf16_t* tf  = (bf16_t*)(ws + off); off += NB2;
    int* cnt       = (int*)(ws + off); off += (size_t)NODES * 4 + 64;
    int* offs      = (int*)(ws + off); off += (size_t)NODES * 4 + 64;
    int* off_start = (int*)(ws + off); off += (size_t)NODES * 4 + 64;
    int* cur       = (int*)(ws + off); off += (size_t)NODES * 4 + 64;
    int* bsum      = (int*)(ws + off); off += 256 * 4;
    int* bofs      = (int*)(ws + off); off += 256 * 4;
    int* srcs      = (int*)(ws + off); off += (size_t)NEDGE * 4;
    float* xres = (float*)d_out;   // d_out doubles as x_res scratch
    float* outp = (float*)d_out;

    dim3 blk(256);
    int gB = (M + 127) / 128;             // 391
    int gE = (NEDGE + 255) / 256;         // 3125

    prep_weights<<<9, blk, 0, stream>>>(W_lin, Wa1, Wa2, Wb1, Wb2, Wg1, Wg2, Wf1, Wf2, wt);

    // --- counting sort of edges by dst (scatter -> gather) ---
    hipMemsetAsync(cnt, 0, (size_t)NODES * 4, stream);
    hist_kernel<<<gE, blk, 0, stream>>>(ei, cnt);
    scan1_kernel<<<NBLK_SCAN, blk, 0, stream>>>(cnt, offs, bsum);
    scan2_kernel<<<1, blk, 0, stream>>>(bsum, bofs);
    scan3_kernel<<<NBLK_SCAN, blk, 0, stream>>>(offs, bofs, off_start, cur);
    reorder_kernel<<<gE, blk, 0, stream>>>(ei, cur, srcs);

    // h = x @ W_lin + b_lin  (fp32 in, bf16 out)
    gemm128<0, true,  true,  false><<<gB, blk, 0, stream>>>(x, wt + 0 * 16384, b_lin, h, nullptr, M);
    // x_res = LN(h)
    ln_kernel<<<(M + 3) / 4, blk, 0, stream>>>(h, ln_g, ln_b, xres, M);
    // first-layer branches
    gemm128<1, false, true, false><<<gB, blk, 0, stream>>>(h, wt + 1 * 16384, ba1, ta, nullptr, M);
    gemm128<1, false, true, false><<<gB, blk, 0, stream>>>(h, wt + 3 * 16384, bb1, tb, nullptr, M);
    gemm128<2, false, true, false><<<gB, blk, 0, stream>>>(h, wt + 5 * 16384, bg1, tg, nullptr, M);
    // second-layer branches
    gemm128<3, false, true, false><<<gB, blk, 0, stream>>>(ta, wt + 2 * 16384, ba2, al, nullptr, M);
    gemm128<3, false, true, false><<<gB, blk, 0, stream>>>(tb, wt + 4 * 16384, bb2, be, nullptr, M);
    gemm128<0, false, true, false><<<gB, blk, 0, stream>>>(tg, wt + 6 * 16384, bg2, ga, nullptr, M);
    // gather + y fused
    gather_y_kernel<<<(M + 3) / 4, blk, 0, stream>>>(off_start, cnt, srcs, h, al, be, ga, deg, yv, M);
    // final MLP + residual
    gemm128<2, false, true,  false><<<gB, blk, 0, stream>>>(yv, wt + 7 * 16384, bf1, tf, nullptr, M);
    gemm128<0, false, false, true ><<<gB, blk, 0, stream>>>(tf, wt + 8 * 16384, bf2, outp, xres, M);
}

// Round 3
// 465.516 us; speedup vs baseline: 3.5929x; 1.0143x over previous
//
#include <hip/hip_runtime.h>
#include <hip/hip_bf16.h>
#include <math.h>

#define NODES 50000
#define NEDGE 800000
#define NBLK_SCAN ((NODES + 255) / 256)   // 196

typedef __bf16 bf16_t;
typedef __bf16 bf16x8 __attribute__((ext_vector_type(8)));
typedef float floatx4 __attribute__((ext_vector_type(4)));

__device__ __forceinline__ float bfbits2f(unsigned int hi16) {
    union { unsigned int u; float f; } c; c.u = hi16; return c.f;
}
__device__ __forceinline__ unsigned short f2bfbits(float f) {
    bf16_t b = (bf16_t)f; unsigned short u;
    __builtin_memcpy(&u, &b, 2); return u;
}

// 0=none, 1=relu, 2=gelu(erf, exact), 3=softplus
template<int ACT>
__device__ __forceinline__ float act_fn(float v) {
    if (ACT == 1) return fmaxf(v, 0.f);
    if (ACT == 2) return 0.5f * v * (1.f + erff(v * 0.70710678118654752f));
    if (ACT == 3) return (v > 20.f) ? v : log1pf(expf(v));
    return v;
}

// ---------------------------------------------------------------------------
// Weight prep: 9 matrices W[k][n] fp32 -> Wt[n][k] bf16 (transposed)
// ---------------------------------------------------------------------------
__global__ __launch_bounds__(256) void prep_weights(
    const float* __restrict__ w0, const float* __restrict__ w1,
    const float* __restrict__ w2, const float* __restrict__ w3,
    const float* __restrict__ w4, const float* __restrict__ w5,
    const float* __restrict__ w6, const float* __restrict__ w7,
    const float* __restrict__ w8, bf16_t* __restrict__ wt)
{
    const float* Ws[9] = {w0, w1, w2, w3, w4, w5, w6, w7, w8};
    const float* W = Ws[blockIdx.x];
    bf16_t* o = wt + blockIdx.x * 16384;
    for (int idx = threadIdx.x; idx < 16384; idx += 256) {
        int k = idx >> 7, n = idx & 127;
        o[n * 128 + k] = (bf16_t)W[idx];
    }
}

// ---------------------------------------------------------------------------
// Shared GEMM building blocks.  LDS tiles: As/Bs 128x128 bf16, XOR-swizzled:
// element (row,col) at row*128 + ((col>>3)^(row&15))*8 + (col&7)
// ---------------------------------------------------------------------------
__device__ __forceinline__ void load_w_regs(const bf16_t* __restrict__ W,
                                            uint4 (&wr)[8], int t)
{
    for (int i = 0; i < 8; ++i) {
        int c = t + i * 256;
        int row = c >> 4, g = c & 15;
        wr[i] = *(const uint4*)(W + row * 128 + g * 8);
    }
}
__device__ __forceinline__ void store_w_regs(const uint4 (&wr)[8],
                                             bf16_t* Bs, int t)
{
    for (int i = 0; i < 8; ++i) {
        int c = t + i * 256;
        int row = c >> 4, g = c & 15;
        *(uint4*)&Bs[row * 128 + ((g ^ (row & 15)) * 8)] = wr[i];
    }
}
// direct global bf16 [M,128] -> As (guarded rows)
__device__ __forceinline__ void stage_bf16(const bf16_t* __restrict__ A,
                                           bf16_t* As, int t, int r0, int M)
{
    for (int i = 0; i < 8; ++i) {
        int c = t + i * 256;
        int row = c >> 4, g = c & 15;
        int gr = r0 + row;
        uint4 v = make_uint4(0, 0, 0, 0);
        if (gr < M) v = *(const uint4*)(A + (size_t)gr * 128 + g * 8);
        *(uint4*)&As[row * 128 + ((g ^ (row & 15)) * 8)] = v;
    }
}
// global fp32 [M,128] -> As bf16 (guarded rows)
__device__ __forceinline__ void stage_f32(const float* __restrict__ A,
                                          bf16_t* As, int t, int r0, int M)
{
    for (int i = 0; i < 16; ++i) {
        int c = t + i * 256;
        int row = c >> 5, c4 = c & 31;
        int gr = r0 + row;
        float4 v = make_float4(0.f, 0.f, 0.f, 0.f);
        if (gr < M) v = *(const float4*)(A + (size_t)gr * 128 + c4 * 4);
        int g = c4 >> 1, half = c4 & 1;
        uint2 p;
        p.x = (unsigned)f2bfbits(v.x) | ((unsigned)f2bfbits(v.y) << 16);
        p.y = (unsigned)f2bfbits(v.z) | ((unsigned)f2bfbits(v.w) << 16);
        *(uint2*)&As[row * 128 + ((g ^ (row & 15)) * 8) + half * 4] = p;
    }
}

__device__ __forceinline__ void kloop(const bf16_t* As, const bf16_t* Bs,
                                      floatx4 (&acc)[4][4], int lane, int wave)
{
    const int wm = (wave & 1) * 64, wn = (wave >> 1) * 64;
    const int l15 = lane & 15, quad = lane >> 4;
    for (int mi = 0; mi < 4; ++mi)
        for (int ni = 0; ni < 4; ++ni)
            for (int r = 0; r < 4; ++r) acc[mi][ni][r] = 0.f;
    for (int kc = 0; kc < 4; ++kc) {
        const int kg = kc * 4 + quad;
        bf16x8 a[4], b[4];
        for (int mi = 0; mi < 4; ++mi) {
            int row = wm + mi * 16 + l15;
            a[mi] = *(const bf16x8*)&As[row * 128 + ((kg ^ (row & 15)) * 8)];
        }
        for (int ni = 0; ni < 4; ++ni) {
            int row = wn + ni * 16 + l15;
            b[ni] = *(const bf16x8*)&Bs[row * 128 + ((kg ^ (row & 15)) * 8)];
        }
        for (int mi = 0; mi < 4; ++mi)
            for (int ni = 0; ni < 4; ++ni)
                acc[mi][ni] = __builtin_amdgcn_mfma_f32_16x16x32_bf16(
                    a[mi], b[ni], acc[mi][ni], 0, 0, 0);
    }
}

// write activated C back into As (swizzled bf16)
template<int ACT>
__device__ __forceinline__ void write_As(bf16_t* As, floatx4 (&acc)[4][4],
                                         const float* __restrict__ bias,
                                         int lane, int wave)
{
    const int wm = (wave & 1) * 64, wn = (wave >> 1) * 64;
    const int l15 = lane & 15, quad = lane >> 4;
    for (int mi = 0; mi < 4; ++mi)
        for (int r = 0; r < 4; ++r) {
            int row = wm + mi * 16 + quad * 4 + r;
            for (int ni = 0; ni < 4; ++ni) {
                int col = wn + ni * 16 + l15;
                float v = act_fn<ACT>(acc[mi][ni][r] + bias[col]);
                As[row * 128 + (((col >> 3) ^ (row & 15)) << 3) + (col & 7)] = (bf16_t)v;
            }
        }
}

// write activated C to global (bf16 or fp32, optional bf16 residual)
template<int ACT, bool OUT_BF16, bool ADD_RES>
__device__ __forceinline__ void epi_global(floatx4 (&acc)[4][4],
    const float* __restrict__ bias, void* __restrict__ Out,
    const bf16_t* __restrict__ res, int r0, int M, int lane, int wave)
{
    const int wm = (wave & 1) * 64, wn = (wave >> 1) * 64;
    const int l15 = lane & 15, quad = lane >> 4;
    for (int mi = 0; mi < 4; ++mi)
        for (int r = 0; r < 4; ++r) {
            int row = wm + mi * 16 + quad * 4 + r;
            int gr = r0 + row;
            if (gr < M) {
                for (int ni = 0; ni < 4; ++ni) {
                    int col = wn + ni * 16 + l15;
                    float v = act_fn<ACT>(acc[mi][ni][r] + bias[col]);
                    if (ADD_RES) v += (float)res[(size_t)gr * 128 + col];
                    if (OUT_BF16) ((bf16_t*)Out)[(size_t)gr * 128 + col] = (bf16_t)v;
                    else          ((float*)Out)[(size_t)gr * 128 + col] = v;
                }
            }
        }
}

// ---------------------------------------------------------------------------
// Fused MLP chain: h = x@W0+b; LN(h)->xres; a-branch; b-branch; g-branch.
// As holds the working activation tile; Bs the current weight; next weight
// prefetched into VGPRs during each K-loop.
// ---------------------------------------------------------------------------
__global__ __launch_bounds__(256, 2) void fused_mlp(
    const float* __restrict__ x, const bf16_t* __restrict__ wt,
    const float* __restrict__ b_lin,
    const float* __restrict__ ba1, const float* __restrict__ ba2,
    const float* __restrict__ bb1, const float* __restrict__ bb2,
    const float* __restrict__ bg1, const float* __restrict__ bg2,
    const float* __restrict__ ln_g, const float* __restrict__ ln_b,
    bf16_t* __restrict__ h, bf16_t* __restrict__ al, bf16_t* __restrict__ be,
    bf16_t* __restrict__ ga, bf16_t* __restrict__ xres, int M)
{
    __shared__ __align__(16) bf16_t As[128 * 128];
    __shared__ __align__(16) bf16_t Bs[128 * 128];
    const int t = threadIdx.x;
    const int r0 = blockIdx.x * 128;
    const int lane = t & 63, wave = t >> 6;
    uint4 wr[8];
    floatx4 acc[4][4];

    // stage x -> As, W_lin -> Bs; prefetch Wa1
    stage_f32(x, As, t, r0, M);
    load_w_regs(wt + 0 * 16384, wr, t);
    store_w_regs(wr, Bs, t);
    load_w_regs(wt + 1 * 16384, wr, t);          // prefetch Wa1
    __syncthreads();

    // s0: h = x@W_lin + b_lin
    kloop(As, Bs, acc, lane, wave);
    epi_global<0, true, false>(acc, b_lin, h, nullptr, r0, M, lane, wave);
    __syncthreads();
    write_As<0>(As, acc, b_lin, lane, wave);     // As <- h
    store_w_regs(wr, Bs, t);                     // Bs <- Wa1
    __syncthreads();

    // LN(h) -> xres (bf16); reads As only
    {
        int row = t >> 1, half = t & 1;
        bf16x8 regs[8];
        float s = 0.f, sq = 0.f;
        for (int i = 0; i < 8; ++i) {
            int gi = half * 8 + i;
            regs[i] = *(const bf16x8*)&As[row * 128 + ((gi ^ (row & 15)) * 8)];
            for (int k = 0; k < 8; ++k) {
                float f = (float)regs[i][k]; s += f; sq += f * f;
            }
        }
        s  += __shfl_xor(s, 1, 64);
        sq += __shfl_xor(sq, 1, 64);
        float m  = s * (1.f / 128.f);
        float var = fmaxf(sq * (1.f / 128.f) - m * m, 0.f);
        float rs = rsqrtf(var + 1e-5f);
        int gr = r0 + row;
        if (gr < M) {
            for (int i = 0; i < 8; ++i) {
                int col0 = half * 64 + i * 8;
                unsigned short ob[8];
                for (int k = 0; k < 8; ++k) {
                    float f = (float)regs[i][k];
                    ob[k] = f2bfbits((f - m) * rs * ln_g[col0 + k] + ln_b[col0 + k]);
                }
                uint4 p;
                p.x = ob[0] | ((unsigned)ob[1] << 16);
                p.y = ob[2] | ((unsigned)ob[3] << 16);
                p.z = ob[4] | ((unsigned)ob[5] << 16);
                p.w = ob[6] | ((unsigned)ob[7] << 16);
                *(uint4*)&xres[(size_t)gr * 128 + col0] = p;
            }
        }
    }

    // s1: ta = relu(h@Wa1 + ba1)
    load_w_regs(wt + 2 * 16384, wr, t);          // prefetch Wa2
    kloop(As, Bs, acc, lane, wave);
    __syncthreads();
    write_As<1>(As, acc, ba1, lane, wave);
    store_w_regs(wr, Bs, t);
    __syncthreads();

    // s2: alpha = softplus(ta@Wa2 + ba2) -> global; then restage h
    load_w_regs(wt + 3 * 16384, wr, t);          // prefetch Wb1
    kloop(As, Bs, acc, lane, wave);
    epi_global<3, true, false>(acc, ba2, al, nullptr, r0, M, lane, wave);
    __syncthreads();
    stage_bf16(h, As, t, r0, M);                 // As <- h (L2-warm)
    store_w_regs(wr, Bs, t);
    __syncthreads();

    // s3: tb = relu(h@Wb1 + bb1)
    load_w_regs(wt + 4 * 16384, wr, t);          // prefetch Wb2
    kloop(As, Bs, acc, lane, wave);
    __syncthreads();
    write_As<1>(As, acc, bb1, lane, wave);
    store_w_regs(wr, Bs, t);
    __syncthreads();

    // s4: beta = softplus(tb@Wb2 + bb2) -> global; restage h
    load_w_regs(wt + 5 * 16384, wr, t);          // prefetch Wg1
    kloop(As, Bs, acc, lane, wave);
    epi_global<3, true, false>(acc, bb2, be, nullptr, r0, M, lane, wave);
    __syncthreads();
    stage_bf16(h, As, t, r0, M);
    store_w_regs(wr, Bs, t);
    __syncthreads();

    // s5: tg = gelu(h@Wg1 + bg1)
    load_w_regs(wt + 6 * 16384, wr, t);          // prefetch Wg2
    kloop(As, Bs, acc, lane, wave);
    __syncthreads();
    write_As<2>(As, acc, bg1, lane, wave);
    store_w_regs(wr, Bs, t);
    __syncthreads();

    // s6: gamma = tg@Wg2 + bg2 -> global
    kloop(As, Bs, acc, lane, wave);
    epi_global<0, true, false>(acc, bg2, ga, nullptr, r0, M, lane, wave);
}

// ---------------------------------------------------------------------------
// Fused final MLP: z = gelu(y@Wf1+bf1)@Wf2 + bf2 + xres -> out fp32
// ---------------------------------------------------------------------------
__global__ __launch_bounds__(256, 2) void fused_out(
    const bf16_t* __restrict__ y, const bf16_t* __restrict__ wt,
    const float* __restrict__ bf1, const float* __restrict__ bf2,
    const bf16_t* __restrict__ xres, float* __restrict__ out, int M)
{
    __shared__ __align__(16) bf16_t As[128 * 128];
    __shared__ __align__(16) bf16_t Bs[128 * 128];
    const int t = threadIdx.x;
    const int r0 = blockIdx.x * 128;
    const int lane = t & 63, wave = t >> 6;
    uint4 wr[8];
    floatx4 acc[4][4];

    stage_bf16(y, As, t, r0, M);
    load_w_regs(wt + 7 * 16384, wr, t);
    store_w_regs(wr, Bs, t);
    load_w_regs(wt + 8 * 16384, wr, t);          // prefetch Wf2
    __syncthreads();

    kloop(As, Bs, acc, lane, wave);
    __syncthreads();
    write_As<2>(As, acc, bf1, lane, wave);       // gelu
    store_w_regs(wr, Bs, t);
    __syncthreads();

    kloop(As, Bs, acc, lane, wave);
    epi_global<0, false, true>(acc, bf2, out, xres, r0, M, lane, wave);
}

// ---------------------------------------------------------------------------
// Counting sort of edges by dst: histogram -> scan -> reorder
// ---------------------------------------------------------------------------
__global__ __launch_bounds__(256) void hist_kernel(const int* __restrict__ ei,
                                                   int* __restrict__ cnt)
{
    int e = blockIdx.x * 256 + threadIdx.x;
    if (e < NEDGE) atomicAdd(&cnt[ei[NEDGE + e]], 1);
}

__global__ __launch_bounds__(256) void scan1_kernel(const int* __restrict__ cnt,
        int* __restrict__ offs, int* __restrict__ bsum)
{
    __shared__ int sd[256];
    int tid = threadIdx.x;
    int i = blockIdx.x * 256 + tid;
    int v = (i < NODES) ? cnt[i] : 0;
    sd[tid] = v;
    __syncthreads();
    for (int o = 1; o < 256; o <<= 1) {
        int other = (tid >= o) ? sd[tid - o] : 0;
        __syncthreads();
        sd[tid] += other;
        __syncthreads();
    }
    if (i < NODES) offs[i] = sd[tid] - v;
    if (tid == 255) bsum[blockIdx.x] = sd[255];
}

__global__ __launch_bounds__(256) void scan2_kernel(const int* __restrict__ bsum,
                                                    int* __restrict__ bofs)
{
    __shared__ int sd[256];
    int tid = threadIdx.x;
    int v = (tid < NBLK_SCAN) ? bsum[tid] : 0;
    sd[tid] = v;
    __syncthreads();
    for (int o = 1; o < 256; o <<= 1) {
        int other = (tid >= o) ? sd[tid - o] : 0;
        __syncthreads();
        sd[tid] += other;
        __syncthreads();
    }
    if (tid < NBLK_SCAN) bofs[tid] = sd[tid] - v;
}

__global__ __launch_bounds__(256) void scan3_kernel(const int* __restrict__ offs,
        const int* __restrict__ bofs, int* __restrict__ off_start,
        int* __restrict__ cur)
{
    int i = blockIdx.x * 256 + threadIdx.x;
    if (i < NODES) {
        int v = offs[i] + bofs[blockIdx.x];
        off_start[i] = v;
        cur[i] = v;
    }
}

__global__ __launch_bounds__(256) void reorder_kernel(const int* __restrict__ ei,
        int* __restrict__ cur, int* __restrict__ srcs)
{
    int e = blockIdx.x * 256 + threadIdx.x;
    if (e >= NEDGE) return;
    int dst = ei[NEDGE + e];
    int pos = atomicAdd(&cur[dst], 1);
    srcs[pos] = ei[e];
}

// ---------------------------------------------------------------------------
// Gather + y epilogue: one wave per node; scalar (SGPR) neighbor indices
// so row loads are independent & deeply pipelined.
// ---------------------------------------------------------------------------
__global__ __launch_bounds__(256) void gather_y_kernel(
    const int* __restrict__ off_start, const int* __restrict__ cnt,
    const int* __restrict__ srcs, const bf16_t* __restrict__ h,
    const bf16_t* __restrict__ al, const bf16_t* __restrict__ be,
    const bf16_t* __restrict__ ga, const float* __restrict__ deg,
    bf16_t* __restrict__ y, int M)
{
    int wave = threadIdx.x >> 6, lane = threadIdx.x & 63;
    int node = blockIdx.x * 4 + wave;
    if (node >= M) return;
    int s0 = __builtin_amdgcn_readfirstlane(off_start[node]);
    int n  = __builtin_amdgcn_readfirstlane(cnt[node]);
    float a0 = 0.f, a1 = 0.f;
    int j = 0;
    for (; j + 4 <= n; j += 4) {
        int i0 = srcs[s0 + j + 0];
        int i1 = srcs[s0 + j + 1];
        int i2 = srcs[s0 + j + 2];
        int i3 = srcs[s0 + j + 3];
        unsigned v0 = *(const unsigned*)(h + (size_t)i0 * 128 + lane * 2);
        unsigned v1 = *(const unsigned*)(h + (size_t)i1 * 128 + lane * 2);
        unsigned v2 = *(const unsigned*)(h + (size_t)i2 * 128 + lane * 2);
        unsigned v3 = *(const unsigned*)(h + (size_t)i3 * 128 + lane * 2);
        a0 += bfbits2f(v0 << 16) + bfbits2f(v1 << 16)
            + bfbits2f(v2 << 16) + bfbits2f(v3 << 16);
        a1 += bfbits2f(v0 & 0xffff0000u) + bfbits2f(v1 & 0xffff0000u)
            + bfbits2f(v2 & 0xffff0000u) + bfbits2f(v3 & 0xffff0000u);
    }
    for (; j < n; ++j) {
        int i0 = srcs[s0 + j];
        unsigned v0 = *(const unsigned*)(h + (size_t)i0 * 128 + lane * 2);
        a0 += bfbits2f(v0 << 16);
        a1 += bfbits2f(v0 & 0xffff0000u);
    }
    size_t i0 = (size_t)node * 128 + (size_t)lane * 2;
    unsigned ra = *(const unsigned*)(al + i0);
    unsigned rb = *(const unsigned*)(be + i0);
    unsigned rg = *(const unsigned*)(ga + i0);
    float d = deg[node];
    float al0 = bfbits2f(ra << 16), al1 = bfbits2f(ra & 0xffff0000u);
    float b0  = bfbits2f(rb << 16), b1  = bfbits2f(rb & 0xffff0000u);
    float g0  = bfbits2f(rg << 16), g1  = bfbits2f(rg & 0xffff0000u);
    float y0 = (b0 * a0 + g0) / (al0 + b0 * d);
    float y1 = (b1 * a1 + g1) / (al1 + b1 * d);
    unsigned u0 = f2bfbits(y0), u1 = f2bfbits(y1);
    *(unsigned*)(y + i0) = u0 | (u1 << 16);
}

// ---------------------------------------------------------------------------
extern "C" void kernel_launch(void* const* d_in, const int* in_sizes, int n_in,
                              void* d_out, int out_size, void* d_ws, size_t ws_size,
                              hipStream_t stream)
{
    const float* x    = (const float*)d_in[0];
    const int*   ei   = (const int*)d_in[1];
    const float* deg  = (const float*)d_in[2];
    const float* W_lin = (const float*)d_in[3];  const float* b_lin = (const float*)d_in[4];
    const float* Wa1 = (const float*)d_in[5];    const float* ba1 = (const float*)d_in[6];
    const float* Wa2 = (const float*)d_in[7];    const float* ba2 = (const float*)d_in[8];
    const float* Wb1 = (const float*)d_in[9];    const float* bb1 = (const float*)d_in[10];
    const float* Wb2 = (const float*)d_in[11];   const float* bb2 = (const float*)d_in[12];
    const float* Wg1 = (const float*)d_in[13];   const float* bg1 = (const float*)d_in[14];
    const float* Wg2 = (const float*)d_in[15];   const float* bg2 = (const float*)d_in[16];
    const float* Wf1 = (const float*)d_in[17];   const float* bf1 = (const float*)d_in[18];
    const float* Wf2 = (const float*)d_in[19];   const float* bf2 = (const float*)d_in[20];
    const float* ln_g = (const float*)d_in[21];  const float* ln_b = (const float*)d_in[22];

    const int M = NODES;
    const size_t NB2 = (size_t)M * 128 * 2;   // bf16 [N,128]

    char* ws = (char*)d_ws;
    size_t off = 0;
    bf16_t* wt  = (bf16_t*)(ws + off); off += (size_t)9 * 16384 * 2;
    bf16_t* h   = (bf16_t*)(ws + off); off += NB2;
    bf16_t* al  = (bf16_t*)(ws + off); off += NB2;
    bf16_t* be  = (bf16_t*)(ws + off); off += NB2;
    bf16_t* ga  = (bf16_t*)(ws + off); off += NB2;
    bf16_t* yv  = (bf16_t*)(ws + off); off += NB2;
    bf16_t* xres = (bf16_t*)(ws + off); off += NB2;
    int* cnt       = (int*)(ws + off); off += (size_t)NODES * 4 + 64;
    int* offs      = (int*)(ws + off); off += (size_t)NODES * 4 + 64;
    int* off_start = (int*)(ws + off); off += (size_t)NODES * 4 + 64;
    int* cur       = (int*)(ws + off); off += (size_t)NODES * 4 + 64;
    int* bsum      = (int*)(ws + off); off += 256 * 4;
    int* bofs      = (int*)(ws + off); off += 256 * 4;
    int* srcs      = (int*)(ws + off); off += (size_t)NEDGE * 4;
    float* outp = (float*)d_out;

    dim3 blk(256);
    int gB = (M + 127) / 128;             // 391
    int gE = (NEDGE + 255) / 256;         // 3125

    prep_weights<<<9, blk, 0, stream>>>(W_lin, Wa1, Wa2, Wb1, Wb2, Wg1, Wg2, Wf1, Wf2, wt);

    // counting sort of edges by dst
    hipMemsetAsync(cnt, 0, (size_t)NODES * 4, stream);
    hist_kernel<<<gE, blk, 0, stream>>>(ei, cnt);
    scan1_kernel<<<NBLK_SCAN, blk, 0, stream>>>(cnt, offs, bsum);
    scan2_kernel<<<1, blk, 0, stream>>>(bsum, bofs);
    scan3_kernel<<<NBLK_SCAN, blk, 0, stream>>>(offs, bofs, off_start, cur);
    reorder_kernel<<<gE, blk, 0, stream>>>(ei, cur, srcs);

    // fused 7-GEMM MLP chain (h, LN->xres, alpha, beta, gamma)
    fused_mlp<<<gB, blk, 0, stream>>>(x, wt, b_lin, ba1, ba2, bb1, bb2, bg1, bg2,
                                      ln_g, ln_b, h, al, be, ga, xres, M);
    // gather + y
    gather_y_kernel<<<(M + 3) / 4, blk, 0, stream>>>(off_start, cnt, srcs, h,
                                                     al, be, ga, deg, yv, M);
    // final MLP + residual
    fused_out<<<gB, blk, 0, stream>>>(yv, wt, bf1, bf2, xres, outp, M);
}

// Round 4
// 463.387 us; speedup vs baseline: 3.6095x; 1.0046x over previous
//
#include <hip/hip_runtime.h>
#include <hip/hip_bf16.h>
#include <math.h>

#define NODES 50000
#define NEDGE 800000
#define NBLK_SCAN ((NODES + 255) / 256)   // 196

typedef __bf16 bf16_t;
typedef __bf16 bf16x8 __attribute__((ext_vector_type(8)));
typedef float floatx4 __attribute__((ext_vector_type(4)));

__device__ __forceinline__ float bfbits2f(unsigned int hi16) {
    union { unsigned int u; float f; } c; c.u = hi16; return c.f;
}
__device__ __forceinline__ unsigned short f2bfbits(float f) {
    bf16_t b = (bf16_t)f; unsigned short u;
    __builtin_memcpy(&u, &b, 2); return u;
}

// act: 0=none, 1=relu, 2=gelu(erf), 3=softplus   (wave-uniform `act`)
__device__ __forceinline__ float act_rt(float v, int act) {
    if (act == 1) return fmaxf(v, 0.f);
    if (act == 2) return 0.5f * v * (1.f + erff(v * 0.70710678118654752f));
    if (act == 3) return (v > 20.f) ? v : log1pf(expf(v));
    return v;
}

// ---------------------------------------------------------------------------
// Weight prep: 9 matrices W[k][n] fp32 -> Wt[n][k] bf16 (transposed)
// ---------------------------------------------------------------------------
__global__ __launch_bounds__(256) void prep_weights(
    const float* __restrict__ w0, const float* __restrict__ w1,
    const float* __restrict__ w2, const float* __restrict__ w3,
    const float* __restrict__ w4, const float* __restrict__ w5,
    const float* __restrict__ w6, const float* __restrict__ w7,
    const float* __restrict__ w8, bf16_t* __restrict__ wt)
{
    const float* Ws[9] = {w0, w1, w2, w3, w4, w5, w6, w7, w8};
    const float* W = Ws[blockIdx.x];
    bf16_t* o = wt + blockIdx.x * 16384;
    for (int idx = threadIdx.x; idx < 16384; idx += 256) {
        int k = idx >> 7, n = idx & 127;
        o[n * 128 + k] = (bf16_t)W[idx];
    }
}

// ---------------------------------------------------------------------------
// LDS tile helpers. As/Bs 128x128 bf16, XOR-swizzled:
// element (row,col) at row*128 + ((col>>3)^(row&15))*8 + (col&7)
// ---------------------------------------------------------------------------
__device__ __forceinline__ void load_w_regs(const bf16_t* __restrict__ W,
                                            uint4 (&wr)[8], int t)
{
    for (int i = 0; i < 8; ++i) {
        int c = t + i * 256;
        int row = c >> 4, g = c & 15;
        wr[i] = *(const uint4*)(W + row * 128 + g * 8);
    }
}
__device__ __forceinline__ void store_w_regs(const uint4 (&wr)[8],
                                             bf16_t* Bs, int t)
{
    for (int i = 0; i < 8; ++i) {
        int c = t + i * 256;
        int row = c >> 4, g = c & 15;
        *(uint4*)&Bs[row * 128 + ((g ^ (row & 15)) * 8)] = wr[i];
    }
}
__device__ __forceinline__ void stage_bf16(const bf16_t* __restrict__ A,
                                           bf16_t* As, int t, int r0, int M)
{
    for (int i = 0; i < 8; ++i) {
        int c = t + i * 256;
        int row = c >> 4, g = c & 15;
        int gr = r0 + row;
        uint4 v = make_uint4(0, 0, 0, 0);
        if (gr < M) v = *(const uint4*)(A + (size_t)gr * 128 + g * 8);
        *(uint4*)&As[row * 128 + ((g ^ (row & 15)) * 8)] = v;
    }
}
__device__ __forceinline__ void stage_f32(const float* __restrict__ A,
                                          bf16_t* As, int t, int r0, int M)
{
    for (int i = 0; i < 16; ++i) {
        int c = t + i * 256;
        int row = c >> 5, c4 = c & 31;
        int gr = r0 + row;
        float4 v = make_float4(0.f, 0.f, 0.f, 0.f);
        if (gr < M) v = *(const float4*)(A + (size_t)gr * 128 + c4 * 4);
        int g = c4 >> 1, half = c4 & 1;
        uint2 p;
        p.x = (unsigned)f2bfbits(v.x) | ((unsigned)f2bfbits(v.y) << 16);
        p.y = (unsigned)f2bfbits(v.z) | ((unsigned)f2bfbits(v.w) << 16);
        *(uint2*)&As[row * 128 + ((g ^ (row & 15)) * 8) + half * 4] = p;
    }
}
// coalesced LDS(swizzled) -> global bf16
__device__ __forceinline__ void copy_As_global(const bf16_t* As,
        bf16_t* __restrict__ out, int t, int r0, int M)
{
    for (int i = 0; i < 8; ++i) {
        int c = t + i * 256;
        int row = c >> 4, g = c & 15;
        int gr = r0 + row;
        if (gr < M) {
            uint4 v = *(const uint4*)&As[row * 128 + ((g ^ (row & 15)) * 8)];
            *(uint4*)(out + (size_t)gr * 128 + g * 8) = v;
        }
    }
}

__device__ __forceinline__ void kloop(const bf16_t* As, const bf16_t* Bs,
                                      floatx4 (&acc)[4][4], int lane, int wave)
{
    const int wm = (wave & 1) * 64, wn = (wave >> 1) * 64;
    const int l15 = lane & 15, quad = lane >> 4;
    for (int mi = 0; mi < 4; ++mi)
        for (int ni = 0; ni < 4; ++ni)
            for (int r = 0; r < 4; ++r) acc[mi][ni][r] = 0.f;
    for (int kc = 0; kc < 4; ++kc) {
        const int kg = kc * 4 + quad;
        bf16x8 a[4], b[4];
        for (int mi = 0; mi < 4; ++mi) {
            int row = wm + mi * 16 + l15;
            a[mi] = *(const bf16x8*)&As[row * 128 + ((kg ^ (row & 15)) * 8)];
        }
        for (int ni = 0; ni < 4; ++ni) {
            int row = wn + ni * 16 + l15;
            b[ni] = *(const bf16x8*)&Bs[row * 128 + ((kg ^ (row & 15)) * 8)];
        }
        for (int mi = 0; mi < 4; ++mi)
            for (int ni = 0; ni < 4; ++ni)
                acc[mi][ni] = __builtin_amdgcn_mfma_f32_16x16x32_bf16(
                    a[mi], b[ni], acc[mi][ni], 0, 0, 0);
    }
}

// write activated C back into As (swizzled bf16); conflict-free (measured 0)
__device__ __forceinline__ void write_As(bf16_t* As, floatx4 (&acc)[4][4],
        const float* __restrict__ bias, int lane, int wave, int act)
{
    const int wm = (wave & 1) * 64, wn = (wave >> 1) * 64;
    const int l15 = lane & 15, quad = lane >> 4;
    for (int mi = 0; mi < 4; ++mi)
        for (int r = 0; r < 4; ++r) {
            int row = wm + mi * 16 + quad * 4 + r;
            for (int ni = 0; ni < 4; ++ni) {
                int col = wn + ni * 16 + l15;
                float v = act_rt(acc[mi][ni][r] + bias[col], act);
                As[row * 128 + (((col >> 3) ^ (row & 15)) << 3) + (col & 7)] = (bf16_t)v;
            }
        }
}

// ---------------------------------------------------------------------------
// Kernel A: h = x@W_lin + b_lin (bf16, coalesced) and xres = LN(h) (bf16)
// ---------------------------------------------------------------------------
__global__ __launch_bounds__(256, 2) void h_ln_kernel(
    const float* __restrict__ x, const bf16_t* __restrict__ wt,
    const float* __restrict__ b_lin,
    const float* __restrict__ ln_g, const float* __restrict__ ln_b,
    bf16_t* __restrict__ h, bf16_t* __restrict__ xres, int M)
{
    __shared__ __align__(16) bf16_t As[128 * 128];
    __shared__ __align__(16) bf16_t Bs[128 * 128];
    const int t = threadIdx.x;
    const int r0 = blockIdx.x * 128;
    const int lane = t & 63, wave = t >> 6;
    uint4 wr[8];
    floatx4 acc[4][4];

    stage_f32(x, As, t, r0, M);
    load_w_regs(wt, wr, t);
    store_w_regs(wr, Bs, t);
    __syncthreads();
    kloop(As, Bs, acc, lane, wave);
    __syncthreads();
    write_As(As, acc, b_lin, lane, wave, 0);   // As <- h
    __syncthreads();
    copy_As_global(As, h, t, r0, M);

    // LN(h) from As -> xres (2 threads per row)
    {
        int row = t >> 1, half = t & 1;
        bf16x8 regs[8];
        float s = 0.f, sq = 0.f;
        for (int i = 0; i < 8; ++i) {
            int gi = half * 8 + i;
            regs[i] = *(const bf16x8*)&As[row * 128 + ((gi ^ (row & 15)) * 8)];
            for (int k = 0; k < 8; ++k) {
                float f = (float)regs[i][k]; s += f; sq += f * f;
            }
        }
        s  += __shfl_xor(s, 1, 64);
        sq += __shfl_xor(sq, 1, 64);
        float m  = s * (1.f / 128.f);
        float var = fmaxf(sq * (1.f / 128.f) - m * m, 0.f);
        float rs = rsqrtf(var + 1e-5f);
        int gr = r0 + row;
        if (gr < M) {
            for (int i = 0; i < 8; ++i) {
                int col0 = half * 64 + i * 8;
                unsigned short ob[8];
                for (int k = 0; k < 8; ++k) {
                    float f = (float)regs[i][k];
                    ob[k] = f2bfbits((f - m) * rs * ln_g[col0 + k] + ln_b[col0 + k]);
                }
                uint4 p;
                p.x = ob[0] | ((unsigned)ob[1] << 16);
                p.y = ob[2] | ((unsigned)ob[3] << 16);
                p.z = ob[4] | ((unsigned)ob[5] << 16);
                p.w = ob[6] | ((unsigned)ob[7] << 16);
                *(uint4*)&xres[(size_t)gr * 128 + col0] = p;
            }
        }
    }
}

// ---------------------------------------------------------------------------
// Kernel B: one block = one branch x one 128-row tile. grid = 3*391.
// branch 0: alpha = softplus(relu(h@Wa1+ba1)@Wa2+ba2)
// branch 1: beta  = softplus(relu(h@Wb1+bb1)@Wb2+bb2)
// branch 2: gamma = gelu(h@Wg1+bg1)@Wg2+bg2
// ---------------------------------------------------------------------------
__global__ __launch_bounds__(256, 2) void branch_kernel(
    const bf16_t* __restrict__ h, const bf16_t* __restrict__ wt,
    const float* __restrict__ ba1, const float* __restrict__ ba2,
    const float* __restrict__ bb1, const float* __restrict__ bb2,
    const float* __restrict__ bg1, const float* __restrict__ bg2,
    bf16_t* __restrict__ al, bf16_t* __restrict__ be, bf16_t* __restrict__ ga,
    int M)
{
    __shared__ __align__(16) bf16_t As[128 * 128];
    __shared__ __align__(16) bf16_t Bs[128 * 128];
    const int t = threadIdx.x;
    const int bid = blockIdx.x;
    const int branch = bid % 3;
    const int r0 = (bid / 3) * 128;
    const int lane = t & 63, wave = t >> 6;
    uint4 wr[8];
    floatx4 acc[4][4];

    const bf16_t* w1 = wt + (1 + 2 * branch) * 16384;
    const bf16_t* w2 = wt + (2 + 2 * branch) * 16384;
    const float* bias1 = (branch == 0) ? ba1 : (branch == 1) ? bb1 : bg1;
    const float* bias2 = (branch == 0) ? ba2 : (branch == 1) ? bb2 : bg2;
    bf16_t* out = (branch == 0) ? al : (branch == 1) ? be : ga;
    const int act1 = (branch == 2) ? 2 : 1;
    const int act2 = (branch == 2) ? 0 : 3;

    stage_bf16(h, As, t, r0, M);
    load_w_regs(w1, wr, t);
    store_w_regs(wr, Bs, t);
    load_w_regs(w2, wr, t);        // prefetch second weight
    __syncthreads();

    kloop(As, Bs, acc, lane, wave);
    __syncthreads();
    write_As(As, acc, bias1, lane, wave, act1);
    store_w_regs(wr, Bs, t);
    __syncthreads();

    kloop(As, Bs, acc, lane, wave);
    __syncthreads();
    write_As(As, acc, bias2, lane, wave, act2);
    __syncthreads();
    copy_As_global(As, out, t, r0, M);
}

// ---------------------------------------------------------------------------
// Kernel C: z = gelu(y@Wf1+bf1)@Wf2 + bf2 + xres -> out fp32 (coalesced)
// ---------------------------------------------------------------------------
__global__ __launch_bounds__(256, 2) void fused_out(
    const bf16_t* __restrict__ y, const bf16_t* __restrict__ wt,
    const float* __restrict__ bf1, const float* __restrict__ bf2,
    const bf16_t* __restrict__ xres, float* __restrict__ out, int M)
{
    __shared__ __align__(16) char smem[128 * 128 * 4];
    bf16_t* As = (bf16_t*)smem;
    bf16_t* Bs = As + 128 * 128;
    float*  Cs = (float*)smem;               // aliases As+Bs after final kloop
    const int t = threadIdx.x;
    const int r0 = blockIdx.x * 128;
    const int lane = t & 63, wave = t >> 6;
    uint4 wr[8];
    floatx4 acc[4][4];

    stage_bf16(y, As, t, r0, M);
    load_w_regs(wt + 7 * 16384, wr, t);
    store_w_regs(wr, Bs, t);
    load_w_regs(wt + 8 * 16384, wr, t);      // prefetch Wf2
    __syncthreads();

    kloop(As, Bs, acc, lane, wave);
    __syncthreads();
    write_As(As, acc, bf1, lane, wave, 2);   // gelu
    store_w_regs(wr, Bs, t);
    __syncthreads();

    kloop(As, Bs, acc, lane, wave);
    __syncthreads();                          // everyone done with As/Bs

    // fp32 C (+bias) into LDS, then coalesced float4 stores (+xres)
    {
        const int wm = (wave & 1) * 64, wn = (wave >> 1) * 64;
        const int l15 = lane & 15, quad = lane >> 4;
        for (int mi = 0; mi < 4; ++mi)
            for (int r = 0; r < 4; ++r) {
                int row = wm + mi * 16 + quad * 4 + r;
                for (int ni = 0; ni < 4; ++ni) {
                    int col = wn + ni * 16 + l15;
                    Cs[row * 128 + col] = acc[mi][ni][r] + bf2[col];
                }
            }
    }
    __syncthreads();
    for (int i = 0; i < 16; ++i) {
        int c = t + i * 256;                 // 4096 float4 chunks
        int row = c >> 5, q = c & 31;
        int gr = r0 + row;
        if (gr < M) {
            float4 v = *(const float4*)&Cs[row * 128 + q * 4];
            uint2 xr = *(const uint2*)(xres + (size_t)gr * 128 + q * 4);
            v.x += bfbits2f(xr.x << 16);
            v.y += bfbits2f(xr.x & 0xffff0000u);
            v.z += bfbits2f(xr.y << 16);
            v.w += bfbits2f(xr.y & 0xffff0000u);
            *(float4*)(out + (size_t)gr * 128 + q * 4) = v;
        }
    }
}

// ---------------------------------------------------------------------------
// Counting sort of edges by dst: histogram -> scan -> reorder
// ---------------------------------------------------------------------------
__global__ __launch_bounds__(256) void hist_kernel(const int* __restrict__ ei,
                                                   int* __restrict__ cnt)
{
    int e = blockIdx.x * 256 + threadIdx.x;
    if (e < NEDGE) atomicAdd(&cnt[ei[NEDGE + e]], 1);
}

__global__ __launch_bounds__(256) void scan1_kernel(const int* __restrict__ cnt,
        int* __restrict__ offs, int* __restrict__ bsum)
{
    __shared__ int sd[256];
    int tid = threadIdx.x;
    int i = blockIdx.x * 256 + tid;
    int v = (i < NODES) ? cnt[i] : 0;
    sd[tid] = v;
    __syncthreads();
    for (int o = 1; o < 256; o <<= 1) {
        int other = (tid >= o) ? sd[tid - o] : 0;
        __syncthreads();
        sd[tid] += other;
        __syncthreads();
    }
    if (i < NODES) offs[i] = sd[tid] - v;
    if (tid == 255) bsum[blockIdx.x] = sd[255];
}

__global__ __launch_bounds__(256) void scan2_kernel(const int* __restrict__ bsum,
                                                    int* __restrict__ bofs)
{
    __shared__ int sd[256];
    int tid = threadIdx.x;
    int v = (tid < NBLK_SCAN) ? bsum[tid] : 0;
    sd[tid] = v;
    __syncthreads();
    for (int o = 1; o < 256; o <<= 1) {
        int other = (tid >= o) ? sd[tid - o] : 0;
        __syncthreads();
        sd[tid] += other;
        __syncthreads();
    }
    if (tid < NBLK_SCAN) bofs[tid] = sd[tid] - v;
}

__global__ __launch_bounds__(256) void scan3_kernel(const int* __restrict__ offs,
        const int* __restrict__ bofs, int* __restrict__ off_start,
        int* __restrict__ cur)
{
    int i = blockIdx.x * 256 + threadIdx.x;
    if (i < NODES) {
        int v = offs[i] + bofs[blockIdx.x];
        off_start[i] = v;
        cur[i] = v;
    }
}

__global__ __launch_bounds__(256) void reorder_kernel(const int* __restrict__ ei,
        int* __restrict__ cur, int* __restrict__ srcs)
{
    int e = blockIdx.x * 256 + threadIdx.x;
    if (e >= NEDGE) return;
    int dst = ei[NEDGE + e];
    int pos = atomicAdd(&cur[dst], 1);
    srcs[pos] = ei[e];
}

// ---------------------------------------------------------------------------
// Gather + y epilogue: one wave per node; scalar (SGPR) neighbor indices
// ---------------------------------------------------------------------------
__global__ __launch_bounds__(256) void gather_y_kernel(
    const int* __restrict__ off_start, const int* __restrict__ cnt,
    const int* __restrict__ srcs, const bf16_t* __restrict__ h,
    const bf16_t* __restrict__ al, const bf16_t* __restrict__ be,
    const bf16_t* __restrict__ ga, const float* __restrict__ deg,
    bf16_t* __restrict__ y, int M)
{
    int wave = threadIdx.x >> 6, lane = threadIdx.x & 63;
    int node = blockIdx.x * 4 + wave;
    if (node >= M) return;
    int s0 = __builtin_amdgcn_readfirstlane(off_start[node]);
    int n  = __builtin_amdgcn_readfirstlane(cnt[node]);
    float a0 = 0.f, a1 = 0.f;
    int j = 0;
    for (; j + 4 <= n; j += 4) {
        int i0 = srcs[s0 + j + 0];
        int i1 = srcs[s0 + j + 1];
        int i2 = srcs[s0 + j + 2];
        int i3 = srcs[s0 + j + 3];
        unsigned v0 = *(const unsigned*)(h + (size_t)i0 * 128 + lane * 2);
        unsigned v1 = *(const unsigned*)(h + (size_t)i1 * 128 + lane * 2);
        unsigned v2 = *(const unsigned*)(h + (size_t)i2 * 128 + lane * 2);
        unsigned v3 = *(const unsigned*)(h + (size_t)i3 * 128 + lane * 2);
        a0 += bfbits2f(v0 << 16) + bfbits2f(v1 << 16)
            + bfbits2f(v2 << 16) + bfbits2f(v3 << 16);
        a1 += bfbits2f(v0 & 0xffff0000u) + bfbits2f(v1 & 0xffff0000u)
            + bfbits2f(v2 & 0xffff0000u) + bfbits2f(v3 & 0xffff0000u);
    }
    for (; j < n; ++j) {
        int i0 = srcs[s0 + j];
        unsigned v0 = *(const unsigned*)(h + (size_t)i0 * 128 + lane * 2);
        a0 += bfbits2f(v0 << 16);
        a1 += bfbits2f(v0 & 0xffff0000u);
    }
    size_t i0 = (size_t)node * 128 + (size_t)lane * 2;
    unsigned ra = *(const unsigned*)(al + i0);
    unsigned rb = *(const unsigned*)(be + i0);
    unsigned rg = *(const unsigned*)(ga + i0);
    float d = deg[node];
    float al0 = bfbits2f(ra << 16), al1 = bfbits2f(ra & 0xffff0000u);
    float b0  = bfbits2f(rb << 16), b1  = bfbits2f(rb & 0xffff0000u);
    float g0  = bfbits2f(rg << 16), g1  = bfbits2f(rg & 0xffff0000u);
    float y0 = (b0 * a0 + g0) / (al0 + b0 * d);
    float y1 = (b1 * a1 + g1) / (al1 + b1 * d);
    unsigned u0 = f2bfbits(y0), u1 = f2bfbits(y1);
    *(unsigned*)(y + i0) = u0 | (u1 << 16);
}

// ---------------------------------------------------------------------------
extern "C" void kernel_launch(void* const* d_in, const int* in_sizes, int n_in,
                              void* d_out, int out_size, void* d_ws, size_t ws_size,
                              hipStream_t stream)
{
    const float* x    = (const float*)d_in[0];
    const int*   ei   = (const int*)d_in[1];
    const float* deg  = (const float*)d_in[2];
    const float* W_lin = (const float*)d_in[3];  const float* b_lin = (const float*)d_in[4];
    const float* Wa1 = (const float*)d_in[5];    const float* ba1 = (const float*)d_in[6];
    const float* Wa2 = (const float*)d_in[7];    const float* ba2 = (const float*)d_in[8];
    const float* Wb1 = (const float*)d_in[9];    const float* bb1 = (const float*)d_in[10];
    const float* Wb2 = (const float*)d_in[11];   const float* bb2 = (const float*)d_in[12];
    const float* Wg1 = (const float*)d_in[13];   const float* bg1 = (const float*)d_in[14];
    const float* Wg2 = (const float*)d_in[15];   const float* bg2 = (const float*)d_in[16];
    const float* Wf1 = (const float*)d_in[17];   const float* bf1 = (const float*)d_in[18];
    const float* Wf2 = (const float*)d_in[19];   const float* bf2 = (const float*)d_in[20];
    const float* ln_g = (const float*)d_in[21];  const float* ln_b = (const float*)d_in[22];

    const int M = NODES;
    const size_t NB2 = (size_t)M * 128 * 2;   // bf16 [N,128]

    char* ws = (char*)d_ws;
    size_t off = 0;
    bf16_t* wt  = (bf16_t*)(ws + off); off += (size_t)9 * 16384 * 2;
    bf16_t* h   = (bf16_t*)(ws + off); off += NB2;
    bf16_t* al  = (bf16_t*)(ws + off); off += NB2;
    bf16_t* be  = (bf16_t*)(ws + off); off += NB2;
    bf16_t* ga  = (bf16_t*)(ws + off); off += NB2;
    bf16_t* yv  = (bf16_t*)(ws + off); off += NB2;
    bf16_t* xres = (bf16_t*)(ws + off); off += NB2;
    int* cnt       = (int*)(ws + off); off += (size_t)NODES * 4 + 64;
    int* offs      = (int*)(ws + off); off += (size_t)NODES * 4 + 64;
    int* off_start = (int*)(ws + off); off += (size_t)NODES * 4 + 64;
    int* cur       = (int*)(ws + off); off += (size_t)NODES * 4 + 64;
    int* bsum      = (int*)(ws + off); off += 256 * 4;
    int* bofs      = (int*)(ws + off); off += 256 * 4;
    int* srcs      = (int*)(ws + off); off += (size_t)NEDGE * 4;
    float* outp = (float*)d_out;

    dim3 blk(256);
    int gB = (M + 127) / 128;             // 391
    int gE = (NEDGE + 255) / 256;         // 3125

    prep_weights<<<9, blk, 0, stream>>>(W_lin, Wa1, Wa2, Wb1, Wb2, Wg1, Wg2, Wf1, Wf2, wt);

    // counting sort of edges by dst
    hipMemsetAsync(cnt, 0, (size_t)NODES * 4, stream);
    hist_kernel<<<gE, blk, 0, stream>>>(ei, cnt);
    scan1_kernel<<<NBLK_SCAN, blk, 0, stream>>>(cnt, offs, bsum);
    scan2_kernel<<<1, blk, 0, stream>>>(bsum, bofs);
    scan3_kernel<<<NBLK_SCAN, blk, 0, stream>>>(offs, bofs, off_start, cur);
    reorder_kernel<<<gE, blk, 0, stream>>>(ei, cur, srcs);

    // h = x@W_lin + b_lin ; xres = LN(h)
    h_ln_kernel<<<gB, blk, 0, stream>>>(x, wt, b_lin, ln_g, ln_b, h, xres, M);
    // alpha / beta / gamma (3 branches x 391 row-tiles)
    branch_kernel<<<3 * gB, blk, 0, stream>>>(h, wt, ba1, ba2, bb1, bb2, bg1, bg2,
                                              al, be, ga, M);
    // gather + y
    gather_y_kernel<<<(M + 3) / 4, blk, 0, stream>>>(off_start, cnt, srcs, h,
                                                     al, be, ga, deg, yv, M);
    // final MLP + residual
    fused_out<<<gB, blk, 0, stream>>>(yv, wt, bf1, bf2, xres, outp, M);
}

// Round 5
// 348.279 us; speedup vs baseline: 4.8024x; 1.3305x over previous
//
#include <hip/hip_runtime.h>
#include <hip/hip_bf16.h>
#include <math.h>

#define NODES 50000
#define NEDGE 800000
#define NBLK_SCAN ((NODES + 255) / 256)   // 196

typedef __bf16 bf16_t;
typedef __bf16 bf16x8 __attribute__((ext_vector_type(8)));
typedef float floatx4 __attribute__((ext_vector_type(4)));

__device__ __forceinline__ float bfbits2f(unsigned int hi16) {
    union { unsigned int u; float f; } c; c.u = hi16; return c.f;
}
__device__ __forceinline__ unsigned short f2bfbits(float f) {
    bf16_t b = (bf16_t)f; unsigned short u;
    __builtin_memcpy(&u, &b, 2); return u;
}

// act: 0=none, 1=relu, 2=gelu(tanh-approx, fast exp), 3=softplus(fast)
__device__ __forceinline__ float act_rt(float v, int act) {
    if (act == 1) return fmaxf(v, 0.f);
    if (act == 2) {
        float w = 0.79788456f * (v + 0.044715f * v * v * v);
        float e = __expf(2.f * w);
        float th = 1.f - 2.f / (e + 1.f);          // tanh(w), saturates correctly
        return 0.5f * v * (1.f + th);
    }
    if (act == 3) return fmaxf(v, 0.f) + __logf(1.f + __expf(-fabsf(v)));
    return v;
}

// ---------------------------------------------------------------------------
// Weight prep: 9 matrices W[k][n] fp32 -> Wt[n][k] bf16 (transposed)
// ---------------------------------------------------------------------------
__global__ __launch_bounds__(256) void prep_weights(
    const float* __restrict__ w0, const float* __restrict__ w1,
    const float* __restrict__ w2, const float* __restrict__ w3,
    const float* __restrict__ w4, const float* __restrict__ w5,
    const float* __restrict__ w6, const float* __restrict__ w7,
    const float* __restrict__ w8, bf16_t* __restrict__ wt)
{
    const float* Ws[9] = {w0, w1, w2, w3, w4, w5, w6, w7, w8};
    const float* W = Ws[blockIdx.x];
    bf16_t* o = wt + blockIdx.x * 16384;
    for (int idx = threadIdx.x; idx < 16384; idx += 256) {
        int k = idx >> 7, n = idx & 127;
        o[n * 128 + k] = (bf16_t)W[idx];
    }
}

// ---------------------------------------------------------------------------
// GEMM building blocks, 64-row tile structure.
// Bs: 128x128 bf16 weight, XOR-swizzled (granule g of row r at g^(r&15)).
// Csw: 64x128 bf16 C-bounce tile, same swizzle.
// A-fragments stream from global (16B/lane, no LDS, no barrier).
// ---------------------------------------------------------------------------
__device__ __forceinline__ void load_w_regs(const bf16_t* __restrict__ W,
                                            uint4 (&wr)[8], int t)
{
    for (int i = 0; i < 8; ++i) {
        int c = t + i * 256;
        int row = c >> 4, g = c & 15;
        wr[i] = *(const uint4*)(W + row * 128 + g * 8);
    }
}
__device__ __forceinline__ void store_w_regs(const uint4 (&wr)[8],
                                             bf16_t* Bs, int t)
{
    for (int i = 0; i < 8; ++i) {
        int c = t + i * 256;
        int row = c >> 4, g = c & 15;
        *(uint4*)&Bs[row * 128 + ((g ^ (row & 15)) * 8)] = wr[i];
    }
}

// A-fragments from global bf16 [M,128]; rows clamped (no NaN, unused rows)
__device__ __forceinline__ void afrag_gbf16(const bf16_t* __restrict__ A,
        bf16x8 (&af)[4], int r0, int lane, int wave, int M)
{
    int gr = r0 + wave * 16 + (lane & 15);
    gr = min(gr, M - 1);
    const bf16_t* p = A + (size_t)gr * 128 + (lane >> 4) * 8;
    for (int kc = 0; kc < 4; ++kc)
        af[kc] = *(const bf16x8*)(p + kc * 32);
}

// wave computes 16 rows x 128 cols: acc[ni] = 16x16 tile at cols ni*16
__device__ __forceinline__ void kloop64(const bf16x8 (&af)[4], const bf16_t* Bs,
                                        floatx4 (&acc)[8], int l15, int quad)
{
    for (int ni = 0; ni < 8; ++ni)
        for (int r = 0; r < 4; ++r) acc[ni][r] = 0.f;
    for (int kc = 0; kc < 4; ++kc) {
        int kg = kc * 4 + quad;
        bf16x8 b[8];
        for (int ni = 0; ni < 8; ++ni) {
            int row = ni * 16 + l15;
            b[ni] = *(const bf16x8*)&Bs[row * 128 + ((kg ^ l15) * 8)];
        }
        for (int ni = 0; ni < 8; ++ni)
            acc[ni] = __builtin_amdgcn_mfma_f32_16x16x32_bf16(
                af[kc], b[ni], acc[ni], 0, 0, 0);
    }
}

// activated C -> Csw (swizzled bf16), rows 0..63
__device__ __forceinline__ void write_Csw(bf16_t* Csw, floatx4 (&acc)[8],
        const float (&bias_r)[8], int lane, int wave, int act)
{
    const int l15 = lane & 15, quad = lane >> 4;
    for (int ni = 0; ni < 8; ++ni) {
        int col = ni * 16 + l15;
        for (int r = 0; r < 4; ++r) {
            int row = wave * 16 + quad * 4 + r;
            float v = act_rt(acc[ni][r] + bias_r[ni], act);
            Csw[row * 128 + (((col >> 3) ^ (row & 15)) << 3) + (col & 7)] = (bf16_t)v;
        }
    }
}

// A-fragments for the NEXT gemm, read from Csw
__device__ __forceinline__ void afrag_Csw(const bf16_t* Csw, bf16x8 (&af)[4],
                                          int lane, int wave)
{
    int l15 = lane & 15, quad = lane >> 4;
    int row = wave * 16 + l15;
    for (int kc = 0; kc < 4; ++kc) {
        int kg = kc * 4 + quad;
        af[kc] = *(const bf16x8*)&Csw[row * 128 + ((kg ^ l15) * 8)];
    }
}

// Csw -> global bf16, coalesced uint4
__device__ __forceinline__ void copy_Csw_out(const bf16_t* Csw,
        bf16_t* __restrict__ out, int t, int r0, int M)
{
    for (int i = 0; i < 4; ++i) {
        int c = t + i * 256;
        int row = c >> 4, g = c & 15;
        int gr = r0 + row;
        if (gr < M)
            *(uint4*)(out + (size_t)gr * 128 + g * 8) =
                *(const uint4*)&Csw[row * 128 + ((g ^ (row & 15)) * 8)];
    }
}

// ---------------------------------------------------------------------------
// Kernel A: h = x@W_lin + b_lin ; xres = LN(h).  64-row tiles, grid 782.
// ---------------------------------------------------------------------------
__global__ __launch_bounds__(256, 3) void h_ln_kernel(
    const float* __restrict__ x, const bf16_t* __restrict__ wt,
    const float* __restrict__ b_lin,
    const float* __restrict__ ln_g, const float* __restrict__ ln_b,
    bf16_t* __restrict__ h, bf16_t* __restrict__ xres, int M)
{
    __shared__ __align__(16) char smem[49152];
    bf16_t* Bs  = (bf16_t*)smem;
    bf16_t* Csw = (bf16_t*)(smem + 32768);
    const int t = threadIdx.x;
    const int r0 = blockIdx.x * 64;
    const int lane = t & 63, wave = t >> 6, l15 = lane & 15, quad = lane >> 4;
    uint4 wr[8];
    bf16x8 af[4];
    floatx4 acc[8];
    float bias_r[8];
    for (int ni = 0; ni < 8; ++ni) bias_r[ni] = b_lin[ni * 16 + l15];

    // A-fragments straight from fp32 x
    {
        int gr = min(r0 + wave * 16 + l15, M - 1);
        const float* p = x + (size_t)gr * 128 + quad * 8;
        for (int kc = 0; kc < 4; ++kc) {
            float4 u0 = *(const float4*)(p + kc * 32);
            float4 u1 = *(const float4*)(p + kc * 32 + 4);
            bf16x8 f;
            f[0] = (bf16_t)u0.x; f[1] = (bf16_t)u0.y;
            f[2] = (bf16_t)u0.z; f[3] = (bf16_t)u0.w;
            f[4] = (bf16_t)u1.x; f[5] = (bf16_t)u1.y;
            f[6] = (bf16_t)u1.z; f[7] = (bf16_t)u1.w;
            af[kc] = f;
        }
    }
    load_w_regs(wt, wr, t);
    store_w_regs(wr, Bs, t);
    __syncthreads();
    kloop64(af, Bs, acc, l15, quad);
    write_Csw(Csw, acc, bias_r, lane, wave, 0);
    __syncthreads();

    // LN from Csw: 4 threads per row, 32 cols each; write h and xres coalesced
    int row = t >> 2, p4 = t & 3;
    int gr = r0 + row;
    uint4 raw[4];
    float vals[32];
    float s = 0.f, sq = 0.f;
    for (int i = 0; i < 4; ++i) {
        int lg = p4 * 4 + i;
        raw[i] = *(const uint4*)&Csw[row * 128 + ((lg ^ (row & 15)) * 8)];
        const unsigned* u = (const unsigned*)&raw[i];
        for (int k = 0; k < 4; ++k) {
            float f0 = bfbits2f(u[k] << 16);
            float f1 = bfbits2f(u[k] & 0xffff0000u);
            vals[i * 8 + k * 2] = f0; vals[i * 8 + k * 2 + 1] = f1;
            s += f0 + f1; sq += f0 * f0 + f1 * f1;
        }
    }
    s += __shfl_xor(s, 1, 64);  sq += __shfl_xor(sq, 1, 64);
    s += __shfl_xor(s, 2, 64);  sq += __shfl_xor(sq, 2, 64);
    float m   = s * (1.f / 128.f);
    float var = fmaxf(sq * (1.f / 128.f) - m * m, 0.f);
    float rs  = rsqrtf(var + 1e-5f);
    if (gr < M) {
        for (int i = 0; i < 4; ++i) {
            int lg = p4 * 4 + i;
            *(uint4*)(h + (size_t)gr * 128 + lg * 8) = raw[i];
            unsigned short ob[8];
            for (int k = 0; k < 8; ++k) {
                int col = lg * 8 + k;
                ob[k] = f2bfbits((vals[i * 8 + k] - m) * rs * ln_g[col] + ln_b[col]);
            }
            uint4 o;
            o.x = ob[0] | ((unsigned)ob[1] << 16);
            o.y = ob[2] | ((unsigned)ob[3] << 16);
            o.z = ob[4] | ((unsigned)ob[5] << 16);
            o.w = ob[6] | ((unsigned)ob[7] << 16);
            *(uint4*)(xres + (size_t)gr * 128 + lg * 8) = o;
        }
    }
}

// ---------------------------------------------------------------------------
// Kernel B: one block = one branch x one 64-row tile. grid = 3*782.
// ---------------------------------------------------------------------------
__global__ __launch_bounds__(256, 3) void branch_kernel(
    const bf16_t* __restrict__ h, const bf16_t* __restrict__ wt,
    const float* __restrict__ ba1, const float* __restrict__ ba2,
    const float* __restrict__ bb1, const float* __restrict__ bb2,
    const float* __restrict__ bg1, const float* __restrict__ bg2,
    bf16_t* __restrict__ al, bf16_t* __restrict__ be, bf16_t* __restrict__ ga,
    int M)
{
    __shared__ __align__(16) char smem[49152];
    bf16_t* Bs  = (bf16_t*)smem;
    bf16_t* Csw = (bf16_t*)(smem + 32768);
    const int t = threadIdx.x;
    const int nt = (M + 63) >> 6;            // tiles per branch (782)
    const int branch = blockIdx.x / nt;
    const int r0 = (blockIdx.x % nt) * 64;
    const int lane = t & 63, wave = t >> 6, l15 = lane & 15, quad = lane >> 4;
    uint4 wr[8];
    bf16x8 af[4];
    floatx4 acc[8];

    const bf16_t* w1 = wt + (1 + 2 * branch) * 16384;
    const bf16_t* w2 = wt + (2 + 2 * branch) * 16384;
    const float* b1p = (branch == 0) ? ba1 : (branch == 1) ? bb1 : bg1;
    const float* b2p = (branch == 0) ? ba2 : (branch == 1) ? bb2 : bg2;
    bf16_t* out = (branch == 0) ? al : (branch == 1) ? be : ga;
    const int act1 = (branch == 2) ? 2 : 1;
    const int act2 = (branch == 2) ? 0 : 3;

    float b1_r[8], b2_r[8];
    for (int ni = 0; ni < 8; ++ni) {
        b1_r[ni] = b1p[ni * 16 + l15];
        b2_r[ni] = b2p[ni * 16 + l15];
    }

    afrag_gbf16(h, af, r0, lane, wave, M);
    load_w_regs(w1, wr, t);
    store_w_regs(wr, Bs, t);
    load_w_regs(w2, wr, t);                  // prefetch second weight
    __syncthreads();

    kloop64(af, Bs, acc, l15, quad);
    write_Csw(Csw, acc, b1_r, lane, wave, act1);
    __syncthreads();
    store_w_regs(wr, Bs, t);                 // Bs <- W2
    __syncthreads();

    afrag_Csw(Csw, af, lane, wave);
    kloop64(af, Bs, acc, l15, quad);
    __syncthreads();
    write_Csw(Csw, acc, b2_r, lane, wave, act2);
    __syncthreads();
    copy_Csw_out(Csw, out, t, r0, M);
}

// ---------------------------------------------------------------------------
// Kernel C: z = gelu(y@Wf1+bf1)@Wf2 + bf2 + xres -> out fp32
// ---------------------------------------------------------------------------
__global__ __launch_bounds__(256, 3) void fused_out(
    const bf16_t* __restrict__ y, const bf16_t* __restrict__ wt,
    const float* __restrict__ bf1, const float* __restrict__ bf2,
    const bf16_t* __restrict__ xres, float* __restrict__ out, int M)
{
    __shared__ __align__(16) char smem[49152];
    bf16_t* Bs  = (bf16_t*)smem;
    bf16_t* Csw = (bf16_t*)(smem + 32768);
    float*  Cf  = (float*)smem;              // 64x132 fp32, reuses all of smem
    const int t = threadIdx.x;
    const int r0 = blockIdx.x * 64;
    const int lane = t & 63, wave = t >> 6, l15 = lane & 15, quad = lane >> 4;
    uint4 wr[8];
    bf16x8 af[4];
    floatx4 acc[8];

    float b1_r[8], b2_r[8];
    for (int ni = 0; ni < 8; ++ni) {
        b1_r[ni] = bf1[ni * 16 + l15];
        b2_r[ni] = bf2[ni * 16 + l15];
    }

    afrag_gbf16(y, af, r0, lane, wave, M);
    load_w_regs(wt + 7 * 16384, wr, t);
    store_w_regs(wr, Bs, t);
    load_w_regs(wt + 8 * 16384, wr, t);      // prefetch Wf2
    __syncthreads();

    kloop64(af, Bs, acc, l15, quad);
    write_Csw(Csw, acc, b1_r, lane, wave, 2);   // gelu
    __syncthreads();
    store_w_regs(wr, Bs, t);
    __syncthreads();

    afrag_Csw(Csw, af, lane, wave);
    kloop64(af, Bs, acc, l15, quad);
    __syncthreads();                          // done with Bs & Csw

    for (int ni = 0; ni < 8; ++ni) {
        int col = ni * 16 + l15;
        for (int r = 0; r < 4; ++r) {
            int row = wave * 16 + quad * 4 + r;
            Cf[row * 132 + col] = acc[ni][r] + b2_r[ni];
        }
    }
    __syncthreads();
    for (int i = 0; i < 8; ++i) {
        int c = t + i * 256;                 // 2048 float4 chunks
        int row = c >> 5, q = c & 31;
        int gr = r0 + row;
        if (gr < M) {
            float4 v = *(const float4*)&Cf[row * 132 + q * 4];
            uint2 xr = *(const uint2*)(xres + (size_t)gr * 128 + q * 4);
            v.x += bfbits2f(xr.x << 16);
            v.y += bfbits2f(xr.x & 0xffff0000u);
            v.z += bfbits2f(xr.y << 16);
            v.w += bfbits2f(xr.y & 0xffff0000u);
            *(float4*)(out + (size_t)gr * 128 + q * 4) = v;
        }
    }
}

// ---------------------------------------------------------------------------
// Counting sort of edges by dst: histogram -> scan -> reorder
// ---------------------------------------------------------------------------
__global__ __launch_bounds__(256) void hist_kernel(const int* __restrict__ ei,
                                                   int* __restrict__ cnt)
{
    int e = blockIdx.x * 256 + threadIdx.x;
    if (e < NEDGE) atomicAdd(&cnt[ei[NEDGE + e]], 1);
}

__global__ __launch_bounds__(256) void scan1_kernel(const int* __restrict__ cnt,
        int* __restrict__ offs, int* __restrict__ bsum)
{
    __shared__ int sd[256];
    int tid = threadIdx.x;
    int i = blockIdx.x * 256 + tid;
    int v = (i < NODES) ? cnt[i] : 0;
    sd[tid] = v;
    __syncthreads();
    for (int o = 1; o < 256; o <<= 1) {
        int other = (tid >= o) ? sd[tid - o] : 0;
        __syncthreads();
        sd[tid] += other;
        __syncthreads();
    }
    if (i < NODES) offs[i] = sd[tid] - v;
    if (tid == 255) bsum[blockIdx.x] = sd[255];
}

__global__ __launch_bounds__(256) void scan2_kernel(const int* __restrict__ bsum,
                                                    int* __restrict__ bofs)
{
    __shared__ int sd[256];
    int tid = threadIdx.x;
    int v = (tid < NBLK_SCAN) ? bsum[tid] : 0;
    sd[tid] = v;
    __syncthreads();
    for (int o = 1; o < 256; o <<= 1) {
        int other = (tid >= o) ? sd[tid - o] : 0;
        __syncthreads();
        sd[tid] += other;
        __syncthreads();
    }
    if (tid < NBLK_SCAN) bofs[tid] = sd[tid] - v;
}

__global__ __launch_bounds__(256) void scan3_kernel(const int* __restrict__ offs,
        const int* __restrict__ bofs, int* __restrict__ off_start,
        int* __restrict__ cur)
{
    int i = blockIdx.x * 256 + threadIdx.x;
    if (i < NODES) {
        int v = offs[i] + bofs[blockIdx.x];
        off_start[i] = v;
        cur[i] = v;
    }
}

__global__ __launch_bounds__(256) void reorder_kernel(const int* __restrict__ ei,
        int* __restrict__ cur, int* __restrict__ srcs)
{
    int e = blockIdx.x * 256 + threadIdx.x;
    if (e >= NEDGE) return;
    int dst = ei[NEDGE + e];
    int pos = atomicAdd(&cur[dst], 1);
    srcs[pos] = ei[e];
}

// ---------------------------------------------------------------------------
// Gather + y: one wave per node. Lane quads = 4 edges in flight; 16B/lane
// row loads; quad shuffle-reduce; lanes 0-15 do the y epilogue (16B stores).
// ---------------------------------------------------------------------------
__global__ __launch_bounds__(256) void gather_y_kernel(
    const int* __restrict__ off_start, const int* __restrict__ cnt,
    const int* __restrict__ srcs, const bf16_t* __restrict__ h,
    const bf16_t* __restrict__ al, const bf16_t* __restrict__ be,
    const bf16_t* __restrict__ ga, const float* __restrict__ deg,
    bf16_t* __restrict__ y, int M)
{
    int wave = threadIdx.x >> 6, lane = threadIdx.x & 63;
    int node = blockIdx.x * 4 + wave;
    if (node >= M) return;
    int s0 = __builtin_amdgcn_readfirstlane(off_start[node]);
    int n  = __builtin_amdgcn_readfirstlane(cnt[node]);
    int grp = lane >> 4, c16 = lane & 15;
    float a[8] = {0.f, 0.f, 0.f, 0.f, 0.f, 0.f, 0.f, 0.f};

    for (int j = 0; j < n; j += 8) {
        int e0 = j + grp, e1 = j + 4 + grp;
        int i0 = srcs[s0 + min(e0, n - 1)];
        int i1 = srcs[s0 + min(e1, n - 1)];
        uint4 v0 = *(const uint4*)(h + (size_t)i0 * 128 + c16 * 8);
        uint4 v1 = *(const uint4*)(h + (size_t)i1 * 128 + c16 * 8);
        if (e0 < n) {
            const unsigned* u = (const unsigned*)&v0;
            for (int k = 0; k < 4; ++k) {
                a[2 * k]     += bfbits2f(u[k] << 16);
                a[2 * k + 1] += bfbits2f(u[k] & 0xffff0000u);
            }
        }
        if (e1 < n) {
            const unsigned* u = (const unsigned*)&v1;
            for (int k = 0; k < 4; ++k) {
                a[2 * k]     += bfbits2f(u[k] << 16);
                a[2 * k + 1] += bfbits2f(u[k] & 0xffff0000u);
            }
        }
    }
    for (int k = 0; k < 8; ++k) {
        a[k] += __shfl_xor(a[k], 16, 64);
        a[k] += __shfl_xor(a[k], 32, 64);
    }
    if (lane < 16) {
        size_t i0 = (size_t)node * 128 + (size_t)c16 * 8;
        uint4 ra = *(const uint4*)(al + i0);
        uint4 rb = *(const uint4*)(be + i0);
        uint4 rg = *(const uint4*)(ga + i0);
        float d = deg[node];
        const unsigned* ua = (const unsigned*)&ra;
        const unsigned* ub = (const unsigned*)&rb;
        const unsigned* ug = (const unsigned*)&rg;
        unsigned short o[8];
        for (int k = 0; k < 4; ++k) {
            float a0 = bfbits2f(ua[k] << 16), a1 = bfbits2f(ua[k] & 0xffff0000u);
            float b0 = bfbits2f(ub[k] << 16), b1 = bfbits2f(ub[k] & 0xffff0000u);
            float g0 = bfbits2f(ug[k] << 16), g1 = bfbits2f(ug[k] & 0xffff0000u);
            o[2 * k]     = f2bfbits((b0 * a[2 * k]     + g0) / (a0 + b0 * d));
            o[2 * k + 1] = f2bfbits((b1 * a[2 * k + 1] + g1) / (a1 + b1 * d));
        }
        uint4 ov;
        ov.x = o[0] | ((unsigned)o[1] << 16);
        ov.y = o[2] | ((unsigned)o[3] << 16);
        ov.z = o[4] | ((unsigned)o[5] << 16);
        ov.w = o[6] | ((unsigned)o[7] << 16);
        *(uint4*)(y + i0) = ov;
    }
}

// ---------------------------------------------------------------------------
extern "C" void kernel_launch(void* const* d_in, const int* in_sizes, int n_in,
                              void* d_out, int out_size, void* d_ws, size_t ws_size,
                              hipStream_t stream)
{
    const float* x    = (const float*)d_in[0];
    const int*   ei   = (const int*)d_in[1];
    const float* deg  = (const float*)d_in[2];
    const float* W_lin = (const float*)d_in[3];  const float* b_lin = (const float*)d_in[4];
    const float* Wa1 = (const float*)d_in[5];    const float* ba1 = (const float*)d_in[6];
    const float* Wa2 = (const float*)d_in[7];    const float* ba2 = (const float*)d_in[8];
    const float* Wb1 = (const float*)d_in[9];    const float* bb1 = (const float*)d_in[10];
    const float* Wb2 = (const float*)d_in[11];   const float* bb2 = (const float*)d_in[12];
    const float* Wg1 = (const float*)d_in[13];   const float* bg1 = (const float*)d_in[14];
    const float* Wg2 = (const float*)d_in[15];   const float* bg2 = (const float*)d_in[16];
    const float* Wf1 = (const float*)d_in[17];   const float* bf1 = (const float*)d_in[18];
    const float* Wf2 = (const float*)d_in[19];   const float* bf2 = (const float*)d_in[20];
    const float* ln_g = (const float*)d_in[21];  const float* ln_b = (const float*)d_in[22];

    const int M = NODES;
    const size_t NB2 = (size_t)M * 128 * 2;   // bf16 [N,128]

    char* ws = (char*)d_ws;
    size_t off = 0;
    bf16_t* wt  = (bf16_t*)(ws + off); off += (size_t)9 * 16384 * 2;
    bf16_t* h   = (bf16_t*)(ws + off); off += NB2;
    bf16_t* al  = (bf16_t*)(ws + off); off += NB2;
    bf16_t* be  = (bf16_t*)(ws + off); off += NB2;
    bf16_t* ga  = (bf16_t*)(ws + off); off += NB2;
    bf16_t* yv  = (bf16_t*)(ws + off); off += NB2;
    bf16_t* xres = (bf16_t*)(ws + off); off += NB2;
    int* cnt       = (int*)(ws + off); off += (size_t)NODES * 4 + 64;
    int* offs      = (int*)(ws + off); off += (size_t)NODES * 4 + 64;
    int* off_start = (int*)(ws + off); off += (size_t)NODES * 4 + 64;
    int* cur       = (int*)(ws + off); off += (size_t)NODES * 4 + 64;
    int* bsum      = (int*)(ws + off); off += 256 * 4;
    int* bofs      = (int*)(ws + off); off += 256 * 4;
    int* srcs      = (int*)(ws + off); off += (size_t)NEDGE * 4;
    float* outp = (float*)d_out;

    dim3 blk(256);
    int gT = (M + 63) / 64;               // 782 row-tiles
    int gE = (NEDGE + 255) / 256;         // 3125

    prep_weights<<<9, blk, 0, stream>>>(W_lin, Wa1, Wa2, Wb1, Wb2, Wg1, Wg2, Wf1, Wf2, wt);

    // counting sort of edges by dst
    hipMemsetAsync(cnt, 0, (size_t)NODES * 4, stream);
    hist_kernel<<<gE, blk, 0, stream>>>(ei, cnt);
    scan1_kernel<<<NBLK_SCAN, blk, 0, stream>>>(cnt, offs, bsum);
    scan2_kernel<<<1, blk, 0, stream>>>(bsum, bofs);
    scan3_kernel<<<NBLK_SCAN, blk, 0, stream>>>(offs, bofs, off_start, cur);
    reorder_kernel<<<gE, blk, 0, stream>>>(ei, cur, srcs);

    // h = x@W_lin + b_lin ; xres = LN(h)
    h_ln_kernel<<<gT, blk, 0, stream>>>(x, wt, b_lin, ln_g, ln_b, h, xres, M);
    // alpha / beta / gamma: 3 branches x 782 tiles
    branch_kernel<<<3 * gT, blk, 0, stream>>>(h, wt, ba1, ba2, bb1, bb2, bg1, bg2,
                                              al, be, ga, M);
    // gather + y
    gather_y_kernel<<<(M + 3) / 4, blk, 0, stream>>>(off_start, cnt, srcs, h,
                                                     al, be, ga, deg, yv, M);
    // final MLP + residual
    fused_out<<<gT, blk, 0, stream>>>(yv, wt, bf1, bf2, xres, outp, M);
}